// Round 1
// 330.039 us; speedup vs baseline: 1.0843x; 1.0843x over previous
//
#include <hip/hip_runtime.h>
#include <hip/hip_bf16.h>

typedef __hip_bfloat16 bf16;
typedef __attribute__((ext_vector_type(8))) __bf16 bf16x8;
typedef __attribute__((ext_vector_type(4))) float f32x4;

__device__ __forceinline__ float toF(bf16 v) { return __bfloat162float(v); }

// dual-dtype load: dt=1 -> underlying memory is fp32; dt=0 -> bf16
__device__ __forceinline__ float ldf(const void* p, size_t i, int dt) {
  return dt ? ((const float*)p)[i] : __bfloat162float(((const bf16*)p)[i]);
}
__device__ __forceinline__ ushort toBF(float f) {
  union { bf16 b; ushort u; } cv; cv.b = __float2bfloat16(f); return cv.u;
}

// ---------------- dtype detection ----------------
__global__ void detect_dtype(const void* x, int n, int* flag) {
  __shared__ int s;
  if (threadIdx.x == 0) s = 0;
  __syncthreads();
  const bf16* xb = (const bf16*)x;
  int bad = 0;
  for (int i = threadIdx.x; i < n; i += 256) {
    float v = __bfloat162float(xb[i]);
    if (!(fabsf(v) < 1e6f)) bad = 1;
  }
  if (bad) atomicOr(&s, 1);
  __syncthreads();
  if (threadIdx.x == 0) flag[0] = s;
}

// ---------------- CSR build (real edges only; self-loops analytic in agg) -------------
__global__ void count_rank(const int* __restrict__ ei, int E,
                           int* __restrict__ cnt, int* __restrict__ rank) {
  int e = blockIdx.x * blockDim.x + threadIdx.x;
  if (e >= E) return;
  int d = ei[E + e];
  rank[e] = atomicAdd(&cnt[d], 1);
}

__global__ __launch_bounds__(256) void scan_reduce(const int* __restrict__ cnt, int n, int* __restrict__ csum) {
  int base = blockIdx.x * 1024;
  int t = threadIdx.x;
  int s = 0;
#pragma unroll
  for (int j = 0; j < 4; j++) {
    int i = base + t * 4 + j;
    if (i < n) s += cnt[i];
  }
#pragma unroll
  for (int off = 32; off > 0; off >>= 1) s += __shfl_down(s, off, 64);
  __shared__ int ws[4];
  if ((t & 63) == 0) ws[t >> 6] = s;
  __syncthreads();
  if (t == 0) csum[blockIdx.x] = ws[0] + ws[1] + ws[2] + ws[3];
}

__global__ __launch_bounds__(256) void scan_top(int* __restrict__ csum, int nb, int* __restrict__ rowstart, int n) {
  __shared__ int sc[256];
  int t = threadIdx.x;
  int v0 = (t < nb) ? csum[t] : 0;
  sc[t] = v0;
  for (int off = 1; off < 256; off <<= 1) {
    __syncthreads();
    int v = (t >= off) ? sc[t - off] : 0;
    __syncthreads();
    sc[t] += v;
  }
  __syncthreads();
  if (t < nb) csum[t] = sc[t] - v0;  // exclusive
  if (t == 0) rowstart[n] = sc[255]; // total
}

__global__ __launch_bounds__(256) void scan_down(const int* __restrict__ cnt, int n,
                                                 const int* __restrict__ csum,
                                                 int* __restrict__ rowstart) {
  int base = blockIdx.x * 1024;
  int t = threadIdx.x, lane = t & 63, w = t >> 6;
  int v[4];
#pragma unroll
  for (int j = 0; j < 4; j++) {
    int i = base + t * 4 + j;
    v[j] = (i < n) ? cnt[i] : 0;
  }
  int s1 = v[0], s2 = s1 + v[1], s3 = s2 + v[2], s4 = s3 + v[3];
  int x = s4;
#pragma unroll
  for (int off = 1; off < 64; off <<= 1) {
    int y = __shfl_up(x, off, 64);
    if (lane >= off) x += y;
  }
  int texcl = x - s4;
  __shared__ int ws[4];
  if (lane == 63) ws[w] = x;
  __syncthreads();
  int woff = 0;
  for (int i = 0; i < 4; i++) if (i < w) woff += ws[i];
  int b0 = csum[blockIdx.x] + woff + texcl;
  int e0 = b0, e1 = b0 + s1, e2 = b0 + s2, e3 = b0 + s3;
  int i0 = base + t * 4;
  if (i0 + 0 < n) rowstart[i0 + 0] = e0;
  if (i0 + 1 < n) rowstart[i0 + 1] = e1;
  if (i0 + 2 < n) rowstart[i0 + 2] = e2;
  if (i0 + 3 < n) rowstart[i0 + 3] = e3;
}

__global__ void scatter2(const int* __restrict__ ei, int E,
                         const int* __restrict__ rowstart, const int* __restrict__ rank,
                         int* __restrict__ adj) {
  int e = blockIdx.x * blockDim.x + threadIdx.x;
  if (e >= E) return;
  int s = ei[e], d = ei[E + e];
  adj[rowstart[d] + rank[e]] = s;
}

// ---------------- consolidated parameter pack: Wt0, Wt1, head fp32 table ----------------
// Wt2 layout for direct MFMA frag loads: Wt2[k/8][col][k%8], zero-padded k in [K,Kpad).
__global__ __launch_bounds__(256) void pack_params(
    const void* __restrict__ W0, const void* __restrict__ W1,
    const void* __restrict__ Wn, const void* __restrict__ Wr,
    const void* __restrict__ bn, const void* __restrict__ br,
    const void* __restrict__ Wc, const void* __restrict__ bc,
    ushort* __restrict__ Wt0, ushort* __restrict__ Wt1, float* __restrict__ HW,
    int IN, int Kpad0, const int* __restrict__ dtflag) {
  int dt = dtflag[0];
  int b = blockIdx.x, t = threadIdx.x;
  if (b < 128) {
    // Wt0 column b, K=IN padded to Kpad0
    for (int k = t; k < Kpad0; k += 256) {
      float v = (k < IN) ? ldf(W0, (size_t)k * 128 + b, dt) : 0.f;
      Wt0[((size_t)(k >> 3) * 128 + b) * 8 + (k & 7)] = toBF(v);
    }
  } else if (b < 256) {
    // Wt1 column b-128, K=128
    int c = b - 128;
    if (t < 128) {
      int k = t;
      Wt1[((size_t)(k >> 3) * 128 + c) * 8 + (k & 7)] = toBF(ldf(W1, (size_t)k * 128 + c, dt));
    }
  } else {
    // head fp32 pack: [Wn | Wr | bn | br | Wc | bc]
    int i = (b - 256) * 256 + t;
    int s0 = IN * 128, s1 = s0 + 128 * 128, s2 = s1 + 128, s3 = s2 + 128, s4 = s3 + 256, s5 = s4 + 1;
    if (i >= s5) return;
    float v;
    if (i < s0) v = ldf(Wn, i, dt);
    else if (i < s1) v = ldf(Wr, i - s0, dt);
    else if (i < s2) v = ldf(bn, i - s1, dt);
    else if (i < s3) v = ldf(br, i - s2, dt);
    else if (i < s4) v = ldf(Wc, i - s3, dt);
    else v = ldf(bc, 0, dt);
    HW[i] = v;
  }
}

// ---------------- MFMA GEMM v4: LDS A-panel, fused fp32->bf16 staging ----------------
// C[nrows,128] = A[nrows,K] @ W[K,128]. LDS panel rows are bf16, RB bytes each.
// CVT=true: when dtflag says fp32, stage-convert from fp32 source directly (no pre-pack pass).
// One barrier; K-loop reads A-frags from LDS, W frags from global (L2-resident).
// K-tail cols covered by Wt2 zero-pad (garbage-A x zero-W = 0; A bytes always finite bf16).
template <int RB, bool ALIGN16, bool CVT>
__global__ __launch_bounds__(256) void mfma_gemm4(const void* __restrict__ A0,
                                                  const ushort* __restrict__ Wt2,
                                                  bf16* __restrict__ C,
                                                  float2* __restrict__ as2, float2* __restrict__ ad2,
                                                  const void* __restrict__ aS, const void* __restrict__ aD,
                                                  int nrows, int K, const int* __restrict__ dtflag) {
  __shared__ __align__(16) unsigned char panel[64 * RB + 64];  // +64 pad (zeroed) for tail reads
  int dtg = dtflag[0];
  int tid = threadIdx.x;
  int row0 = blockIdx.x * 64;

  if (CVT && dtg) {
    // ---- stage + convert: contiguous fp32 stream -> bf16 panel ----
    const float* Af = (const float*)A0 + (size_t)row0 * K;
    size_t availf = (size_t)nrows * K - (size_t)row0 * K;
    size_t pf = availf < (size_t)(64 * K) ? availf : (size_t)(64 * K);
    int nch = (int)(pf >> 2);
    for (int c = tid; c < nch; c += 256) {
      float4 v = ((const float4*)Af)[c];
      uint2 o;
      o.x = (uint)toBF(v.x) | ((uint)toBF(v.y) << 16);
      o.y = (uint)toBF(v.z) | ((uint)toBF(v.w) << 16);
      *(uint2*)&panel[(size_t)c << 3] = o;
    }
    // scalar fixup for non-multiple-of-4 float tail
    for (int f = (nch << 2) + tid; f < (int)pf; f += 256)
      ((ushort*)panel)[f] = toBF(Af[f]);
    // zero everything past valid elems (absent rows + pad)
    for (int u2 = (int)pf + tid; u2 < (64 * RB + 64) / 2; u2 += 256)
      ((ushort*)panel)[u2] = 0;
  } else {
    // ---- stage panel: contiguous bf16 bytes, perfectly coalesced ----
    const unsigned char* A = (const unsigned char*)A0;
    size_t gbase = (size_t)row0 * RB;
    size_t avail = (size_t)nrows * RB - gbase;
    size_t pbytes = avail < (size_t)(64 * RB) ? avail : (size_t)(64 * RB);
    int nchunk = (int)(pbytes >> 4);
    const uint4* gsrc = (const uint4*)(A + gbase);
    for (int c = tid; c < nchunk; c += 256)
      *(uint4*)&panel[(size_t)c << 4] = gsrc[c];
    for (int b = (nchunk << 4) + tid * 4; b < (int)pbytes; b += 1024)
      *(uint*)&panel[b] = *(const uint*)(A + gbase + b);
    for (int b = (int)((pbytes + 3) & ~3ull) + tid * 4; b < 64 * RB + 64; b += 1024)
      *(uint*)&panel[b] = 0u;
  }
  __syncthreads();

  int wave = tid >> 6, lane = tid & 63;
  int m = lane & 15, q = lane >> 4;
  int lrow = wave * 16 + m;
  const unsigned char* prow = &panel[(size_t)lrow * RB];

  f32x4 acc[8];
#pragma unroll
  for (int ct = 0; ct < 8; ct++) acc[ct] = (f32x4){0.f, 0.f, 0.f, 0.f};

  const ushort* wq = Wt2 + (size_t)q * 1024 + (size_t)m * 8;
  int niter = (K + 31) >> 5;
  for (int it = 0; it < niter; it++) {
    bf16x8 av;
    if (ALIGN16) {
      av = *(const bf16x8*)(prow + it * 64 + q * 16);
    } else {
      uint u[4];
#pragma unroll
      for (int j = 0; j < 4; j++) u[j] = *(const uint*)(prow + it * 64 + q * 16 + j * 4);
      __builtin_memcpy(&av, u, 16);
    }
    const ushort* wk = wq + (size_t)it * 4096;
    bf16x8 wv[8];
#pragma unroll
    for (int ct = 0; ct < 8; ct++) wv[ct] = *(const bf16x8*)(wk + ct * 128);
#pragma unroll
    for (int ct = 0; ct < 8; ct++)
      acc[ct] = __builtin_amdgcn_mfma_f32_16x16x32_bf16(av, wv[ct], acc[ct], 0, 0, 0);
  }

  // ---- C writeback (C/D: col=lane&15, row=q*4+r) ----
#pragma unroll
  for (int ct = 0; ct < 8; ct++) {
#pragma unroll
    for (int r = 0; r < 4; r++) {
      int grow = row0 + wave * 16 + q * 4 + r;
      if (grow < nrows) C[(size_t)grow * 128 + ct * 16 + m] = __float2bfloat16(acc[ct][r]);
    }
  }

  // ---- fused attention logits ----
  float aSv[8], aDv[8];
#pragma unroll
  for (int ct = 0; ct < 8; ct++) {
    aSv[ct] = ldf(aS, ct * 16 + m, dtg);
    aDv[ct] = ldf(aD, ct * 16 + m, dtg);
  }
#pragma unroll
  for (int r = 0; r < 4; r++) {
    float s0 = 0.f, s1 = 0.f, d0 = 0.f, d1 = 0.f;
#pragma unroll
    for (int ct = 0; ct < 4; ct++) {
      float v = acc[ct][r];
      s0 += v * aSv[ct]; d0 += v * aDv[ct];
    }
#pragma unroll
    for (int ct = 4; ct < 8; ct++) {
      float v = acc[ct][r];
      s1 += v * aSv[ct]; d1 += v * aDv[ct];
    }
#pragma unroll
    for (int off = 1; off < 16; off <<= 1) {
      s0 += __shfl_xor(s0, off, 64);
      s1 += __shfl_xor(s1, off, 64);
      d0 += __shfl_xor(d0, off, 64);
      d1 += __shfl_xor(d1, off, 64);
    }
    int grow = row0 + wave * 16 + q * 4 + r;
    if (m == 0 && grow < nrows) {
      as2[grow] = make_float2(s0, s1);
      ad2[grow] = make_float2(d0, d1);
    }
  }
}

// ---------------- generic fallback GEMM (any K / dtype) -------
__global__ __launch_bounds__(256) void mfma_gemm_gen(const void* __restrict__ A, const ushort* __restrict__ Wt2,
                                                     bf16* __restrict__ C,
                                                     float2* __restrict__ as2, float2* __restrict__ ad2,
                                                     const void* __restrict__ aS, const void* __restrict__ aD,
                                                     int nrows, int K, const int* __restrict__ dtflag) {
  int dtg = dtflag[0];
  int tid = threadIdx.x;
  int wave = tid >> 6, lane = tid & 63;
  int m = lane & 15, q = lane >> 4;
  int row0 = blockIdx.x * 64;
  int rowA = row0 + wave * 16 + m;
  int rA = rowA < nrows ? rowA : nrows - 1;

  f32x4 acc[8];
#pragma unroll
  for (int ct = 0; ct < 8; ct++) acc[ct] = (f32x4){0.f, 0.f, 0.f, 0.f};

  const ushort* wq = Wt2 + (size_t)q * 1024 + (size_t)m * 8;
  int niter = (K + 31) >> 5;
  for (int it = 0; it < niter; it++) {
    ushort u[8];
#pragma unroll
    for (int j = 0; j < 8; j++) {
      int k = it * 32 + q * 8 + j;
      u[j] = (k < K) ? toBF(ldf(A, (size_t)rA * K + k, dtg)) : (ushort)0;
    }
    bf16x8 av;
    __builtin_memcpy(&av, u, 16);
    const ushort* wk = wq + (size_t)it * 4096;
    bf16x8 wv[8];
#pragma unroll
    for (int ct = 0; ct < 8; ct++) wv[ct] = *(const bf16x8*)(wk + ct * 128);
#pragma unroll
    for (int ct = 0; ct < 8; ct++)
      acc[ct] = __builtin_amdgcn_mfma_f32_16x16x32_bf16(av, wv[ct], acc[ct], 0, 0, 0);
  }
#pragma unroll
  for (int ct = 0; ct < 8; ct++) {
#pragma unroll
    for (int r = 0; r < 4; r++) {
      int grow = row0 + wave * 16 + q * 4 + r;
      if (grow < nrows) C[(size_t)grow * 128 + ct * 16 + m] = __float2bfloat16(acc[ct][r]);
    }
  }
  float aSv[8], aDv[8];
#pragma unroll
  for (int ct = 0; ct < 8; ct++) {
    aSv[ct] = ldf(aS, ct * 16 + m, dtg);
    aDv[ct] = ldf(aD, ct * 16 + m, dtg);
  }
#pragma unroll
  for (int r = 0; r < 4; r++) {
    float s0 = 0.f, s1 = 0.f, d0 = 0.f, d1 = 0.f;
#pragma unroll
    for (int ct = 0; ct < 4; ct++) { float v = acc[ct][r]; s0 += v * aSv[ct]; d0 += v * aDv[ct]; }
#pragma unroll
    for (int ct = 4; ct < 8; ct++) { float v = acc[ct][r]; s1 += v * aSv[ct]; d1 += v * aDv[ct]; }
#pragma unroll
    for (int off = 1; off < 16; off <<= 1) {
      s0 += __shfl_xor(s0, off, 64);
      s1 += __shfl_xor(s1, off, 64);
      d0 += __shfl_xor(d0, off, 64);
      d1 += __shfl_xor(d1, off, 64);
    }
    int grow = row0 + wave * 16 + q * 4 + r;
    if (m == 0 && grow < nrows) {
      as2[grow] = make_float2(s0, s1);
      ad2[grow] = make_float2(d0, d1);
    }
  }
}

// ---------------- GAT aggregate v4: 8-deep gather batching for MLP ----------------
// Latency theory: v3's unroll-4 inner loop holds <=4 random 256B row-gathers in flight;
// VALUBusy 52% / HBM 31% / Mfma 0 => latency-bound. v4 rounds cap up to a multiple of 8
// and issues 8 unguarded gathers into registers before the dependent FMAs. Slots past
// `cap` have weight 0 / src 0 (written by all 64 lanes in phase 1), so extra gathers hit
// the L2-hot row 0 and contribute exactly 0.
#define GCAP 64
__global__ __launch_bounds__(256) void gat_agg4(const bf16* __restrict__ xw,
                                                const float2* __restrict__ as2, const float2* __restrict__ ad2,
                                                const int* __restrict__ rowstart, const int* __restrict__ adj,
                                                const void* __restrict__ bias, bf16* __restrict__ out, int N,
                                                const int* __restrict__ dtflag) {
  __shared__ float2 sW[4][GCAP];
  __shared__ int sS[4][GCAP];
  int dt = dtflag[0];
  int wslot = threadIdx.x >> 6;
  int lane = threadIdx.x & 63;
  int n = (blockIdx.x * blockDim.x + threadIdx.x) >> 6;
  bool act = n < N;
  int r0 = 0, r1 = 0;
  float2 adv = make_float2(0.f, 0.f), asn = make_float2(0.f, 0.f);
  if (act) { r0 = rowstart[n]; r1 = rowstart[n + 1]; adv = ad2[n]; asn = as2[n]; }
  int deg = r1 - r0;

  float es0 = asn.x + adv.x; es0 = es0 > 0.f ? es0 : 0.2f * es0;
  float es1 = asn.y + adv.y; es1 = es1 > 0.f ? es1 : 0.2f * es1;
  float ws0 = __expf(fminf(es0, 60.f)), ws1 = __expf(fminf(es1, 60.f));

  float den0, den1;
  {
    bool v = act && lane < deg;
    int s = v ? adj[r0 + lane] : 0;
    float w0 = 0.f, w1 = 0.f;
    if (v) {
      float2 asv = as2[s];
      float e0 = asv.x + adv.x; e0 = e0 > 0.f ? e0 : 0.2f * e0;
      float e1 = asv.y + adv.y; e1 = e1 > 0.f ? e1 : 0.2f * e1;
      w0 = __expf(fminf(e0, 60.f)); w1 = __expf(fminf(e1, 60.f));
    }
    sW[wslot][lane] = make_float2(w0, w1);
    sS[wslot][lane] = s;
    den0 = w0; den1 = w1;
  }
  for (int i = r0 + GCAP + lane; i < r1; i += 64) {
    int s = adj[i];
    float2 asv = as2[s];
    float e0 = asv.x + adv.x; e0 = e0 > 0.f ? e0 : 0.2f * e0;
    float e1 = asv.y + adv.y; e1 = e1 > 0.f ? e1 : 0.2f * e1;
    den0 += __expf(fminf(e0, 60.f)); den1 += __expf(fminf(e1, 60.f));
  }
#pragma unroll
  for (int off = 32; off > 0; off >>= 1) {
    den0 += __shfl_xor(den0, off, 64);
    den1 += __shfl_xor(den1, off, 64);
  }
  den0 += ws0; den1 += ws1;
  float inv0 = 1.f / (den0 + 1e-16f), inv1 = 1.f / (den1 + 1e-16f);

  const uint* xw32 = (const uint*)xw;
  float wsS = (lane < 32) ? ws0 : ws1;
  uint pvs = act ? xw32[((size_t)n << 6) + lane] : 0;
  float a0 = wsS * __uint_as_float(pvs << 16);
  float a1 = wsS * __uint_as_float(pvs & 0xffff0000u);
  int cap = deg < GCAP ? deg : GCAP;
  int capR = (cap + 7) & ~7;   // wave-uniform; slots [cap,capR) have w=0,s=0
  for (int i = 0; i < capR; i += 8) {
    uint pv[8]; float wsv[8];
#pragma unroll
    for (int j = 0; j < 8; j++) {
      float2 wv = sW[wslot][i + j];
      int s = sS[wslot][i + j];
      wsv[j] = (lane < 32) ? wv.x : wv.y;
      pv[j] = xw32[((size_t)s << 6) + lane];
    }
#pragma unroll
    for (int j = 0; j < 8; j++) {
      a0 += wsv[j] * __uint_as_float(pv[j] << 16);
      a1 += wsv[j] * __uint_as_float(pv[j] & 0xffff0000u);
    }
  }
  for (int i = GCAP; i < deg; i++) {
    int s = adj[r0 + i];
    float2 asv = as2[s];
    float e0 = asv.x + adv.x; e0 = e0 > 0.f ? e0 : 0.2f * e0;
    float e1 = asv.y + adv.y; e1 = e1 > 0.f ? e1 : 0.2f * e1;
    float w0 = __expf(fminf(e0, 60.f)), w1 = __expf(fminf(e1, 60.f));
    uint pv = xw32[((size_t)s << 6) + lane];
    float ws = (lane < 32) ? w0 : w1;
    a0 += ws * __uint_as_float(pv << 16);
    a1 += ws * __uint_as_float(pv & 0xffff0000u);
  }
  if (act) {
    int c0 = 2 * lane;
    float invs = (lane < 32) ? inv0 : inv1;
    float o0 = a0 * invs + ldf(bias, c0, dt);
    float o1 = a1 * invs + ldf(bias, c0 + 1, dt);
    o0 = o0 > 0.f ? o0 : 0.f;
    o1 = o1 > 0.f ? o1 : 0.f;
    uint pk = (uint)toBF(o0) | ((uint)toBF(o1) << 16);
    ((uint*)out)[(size_t)n * 64 + lane] = pk;
  }
}

// ---------------- parallel mean-pool (unnormalized sums; contiguous batch) ----------------
__global__ __launch_bounds__(256) void pool_kernel(const bf16* __restrict__ h, const int* __restrict__ batch,
                                                   float* __restrict__ pooled, int N) {
  int n0 = blockIdx.x * 128;
  int nEnd = n0 + 128 < N ? n0 + 128 : N;
  int col = threadIdx.x & 127, half = threadIdx.x >> 7;
  float acc = 0.f;
  int cur = -1;
  for (int n = n0 + half; n < nEnd; n += 2) {
    int g = batch[n];
    if (g != cur) {
      if (cur >= 0) atomicAdd(&pooled[(size_t)cur * 128 + col], acc);
      acc = 0.f; cur = g;
    }
    acc += toF(h[(size_t)n * 128 + col]);
  }
  if (cur >= 0) atomicAdd(&pooled[(size_t)cur * 128 + col], acc);
}

// ---------------- head v4: fp32-packed weights, no per-load dtype branch ----------------
__global__ __launch_bounds__(512) void head4_kernel(
    const float* __restrict__ pooled, const void* __restrict__ x, const int* __restrict__ batch,
    const float* __restrict__ HW, void* __restrict__ out, int N, int IN,
    const int* __restrict__ dtflag) {
  const float* Wn_f = HW;
  const float* Wr_f = HW + (size_t)IN * 128;
  const float* bn_f = Wr_f + 128 * 128;
  const float* br_f = bn_f + 128;
  const float* Wc_f = br_f + 128;
  const float* bc_f = Wc_f + 256;
  int dt = dtflag[0];
  int b = blockIdx.x;
  int tid = threadIdx.x;
  int t = tid & 127, g = tid >> 7;
  __shared__ int sr0, sr1;
  __shared__ float xs[512];
  __shared__ float pl[128];
  __shared__ float pn[4][128];
  __shared__ float pg[4][128];
  __shared__ float red[128];
  if (tid == 0) {
    int lo = 0, hi = N;
    while (lo < hi) { int mid = (lo + hi) >> 1; if (batch[mid] < b) lo = mid + 1; else hi = mid; }
    sr0 = lo;
  }
  if (tid == 1) {
    int lo = 0, hi = N, b1 = b + 1;
    while (lo < hi) { int mid = (lo + hi) >> 1; if (batch[mid] < b1) lo = mid + 1; else hi = mid; }
    sr1 = lo;
  }
  __syncthreads();
  int r0 = sr0;
  float inv_cnt = 1.f / (float)(sr1 - r0);
  if (tid < 128) pl[tid] = pooled[(size_t)b * 128 + tid] * inv_cnt;
  if (dt) {
    const float* xf = (const float*)x + (size_t)r0 * IN;
    for (int k = tid; k < IN; k += 512) xs[k] = xf[k];
  } else {
    const bf16* xb = (const bf16*)x + (size_t)r0 * IN;
    for (int k = tid; k < IN; k += 512) xs[k] = toF(xb[k]);
  }
  __syncthreads();

  float n0 = 0.f, n1 = 0.f, n2 = 0.f, n3 = 0.f;
  {
    int k = g;
    for (; k + 12 < IN; k += 16) {
      n0 += xs[k]      * Wn_f[(size_t)k * 128 + t];
      n1 += xs[k + 4]  * Wn_f[(size_t)(k + 4) * 128 + t];
      n2 += xs[k + 8]  * Wn_f[(size_t)(k + 8) * 128 + t];
      n3 += xs[k + 12] * Wn_f[(size_t)(k + 12) * 128 + t];
    }
    for (; k < IN; k += 4) n0 += xs[k] * Wn_f[(size_t)k * 128 + t];
  }
  float g0 = 0.f, g1 = 0.f;
  {
    int k = g;
    for (; k + 4 < 128; k += 8) {
      g0 += pl[k]     * Wr_f[(size_t)k * 128 + t];
      g1 += pl[k + 4] * Wr_f[(size_t)(k + 4) * 128 + t];
    }
    for (; k < 128; k += 4) g0 += pl[k] * Wr_f[(size_t)k * 128 + t];
  }
  pn[g][t] = (n0 + n1) + (n2 + n3);
  pg[g][t] = g0 + g1;
  __syncthreads();
  if (tid < 128) {
    float nw = pn[0][t] + pn[1][t] + pn[2][t] + pn[3][t] + bn_f[t];
    nw = nw > 0.f ? nw : 0.f;
    float gg = pg[0][t] + pg[1][t] + pg[2][t] + pg[3][t] + br_f[t];
    gg = gg > 0.f ? gg : 0.f;
    red[t] = gg * Wc_f[t] + nw * Wc_f[128 + t];
  }
  __syncthreads();
  for (int s = 64; s > 0; s >>= 1) {
    if (tid < s) red[tid] += red[tid + s];
    __syncthreads();
  }
  if (tid == 0) {
    float z = red[0] + bc_f[0];
    float r = 1.f / (1.f + __expf(-z));
    if (dt) ((float*)out)[b] = r;
    else ((bf16*)out)[b] = __float2bfloat16(r);
  }
}

extern "C" void kernel_launch(void* const* d_in, const int* in_sizes, int n_in,
                              void* d_out, int out_size, void* d_ws, size_t ws_size,
                              hipStream_t stream) {
  const void* x   = d_in[0];
  const void* W0  = d_in[1];
  const void* aS0 = d_in[2];
  const void* aD0 = d_in[3];
  const void* b0  = d_in[4];
  const void* W1  = d_in[5];
  const void* aS1 = d_in[6];
  const void* aD1 = d_in[7];
  const void* b1  = d_in[8];
  const void* Wn  = d_in[9];
  const void* bn  = d_in[10];
  const void* Wr  = d_in[11];
  const void* br  = d_in[12];
  const void* Wc  = d_in[13];
  const void* bc  = d_in[14];
  const int* ei    = (const int*)d_in[15];
  const int* batch = (const int*)d_in[16];

  const int N = in_sizes[16];
  const int IN = in_sizes[0] / N;
  const int E = in_sizes[15] / 2;
  const int B = out_size;
  const int Kpad0 = (IN + 31) / 32 * 32;   // 320
  const int hw_elems = IN * 128 + 128 * 128 + 128 + 128 + 256 + 1;

  char* w = (char*)d_ws;
  size_t off = 0;
  auto alloc = [&](size_t bytes) { void* p = w + off; off += (bytes + 255) / 256 * 256; return p; };
  int* flag      = (int*)alloc(256);
  bf16* bufA     = (bf16*)alloc((size_t)N * 128 * 2);
  bf16* bufB     = (bf16*)alloc((size_t)N * 128 * 2);
  float2* as2    = (float2*)alloc((size_t)N * 8);
  float2* ad2    = (float2*)alloc((size_t)N * 8);
  int* cnt       = (int*)alloc((size_t)N * 4);
  int* rowstart  = (int*)alloc((size_t)(N + 1) * 4);
  int* rank      = (int*)alloc((size_t)E * 4);
  int* adj       = (int*)alloc((size_t)E * 4);
  int* csum      = (int*)alloc(1024);
  ushort* Wt0    = (ushort*)alloc((size_t)128 * Kpad0 * 2);
  ushort* Wt1    = (ushort*)alloc((size_t)128 * 128 * 2);
  float* pooled  = (float*)alloc((size_t)B * 128 * 4);
  float* HW      = (float*)alloc((size_t)hw_elems * 4);

  int ndet = in_sizes[0] < 4096 ? in_sizes[0] : 4096;
  detect_dtype<<<1, 256, 0, stream>>>(x, ndet, flag);

  hipMemsetAsync(cnt, 0, sizeof(int) * N, stream);
  hipMemsetAsync(pooled, 0, sizeof(float) * (size_t)B * 128, stream);

  const int tb = 256;
  count_rank<<<(E + tb - 1) / tb, tb, 0, stream>>>(ei, E, cnt, rank);
  int nb = (N + 1023) / 1024;
  scan_reduce<<<nb, 256, 0, stream>>>(cnt, N, csum);
  scan_top<<<1, 256, 0, stream>>>(csum, nb, rowstart, N);
  scan_down<<<nb, 256, 0, stream>>>(cnt, N, csum, rowstart);
  scatter2<<<(E + tb - 1) / tb, tb, 0, stream>>>(ei, E, rowstart, rank, adj);

  // one consolidated parameter-pack dispatch: Wt0 (128 blocks) + Wt1 (128) + head table
  int pgrid_params = 256 + (hw_elems + 255) / 256;
  pack_params<<<pgrid_params, 256, 0, stream>>>(W0, W1, Wn, Wr, bn, br, Wc, bc,
                                                Wt0, Wt1, HW, IN, Kpad0, flag);

  int ggrid = (N + 63) / 64;
  int pgrid = (N + 127) / 128;
  int wgrid = ((N * 64) + 255) / 256;

  // Layer 0: fast panel path for the known shape (IN=310), fp32->bf16 conversion fused
  // into LDS staging (no separate pack pass); generic fallback otherwise
  if (IN == 310) {
    mfma_gemm4<620, false, true><<<ggrid, 256, 0, stream>>>(x, Wt0, bufA, as2, ad2, aS0, aD0, N, IN, flag);
  } else {
    mfma_gemm_gen<<<ggrid, 256, 0, stream>>>(x, Wt0, bufA, as2, ad2, aS0, aD0, N, IN, flag);
  }
  gat_agg4<<<wgrid, 256, 0, stream>>>(bufA, as2, ad2, rowstart, adj, b0, bufB, N, flag);

  // Layer 1: bf16 buffer, 256B rows, 16B-aligned
  mfma_gemm4<256, true, false><<<ggrid, 256, 0, stream>>>(bufB, Wt1, bufA, as2, ad2, aS1, aD1, N, 128, flag);
  gat_agg4<<<wgrid, 256, 0, stream>>>(bufA, as2, ad2, rowstart, adj, b1, bufB, N, flag);

  // Head
  pool_kernel<<<pgrid, 256, 0, stream>>>(bufB, batch, pooled, N);
  head4_kernel<<<B, 512, 0, stream>>>(pooled, x, batch, HW, (void*)d_out, N, IN, flag);
}

// Round 2
// 323.370 us; speedup vs baseline: 1.1067x; 1.0206x over previous
//
#include <hip/hip_runtime.h>
#include <hip/hip_bf16.h>

typedef __hip_bfloat16 bf16;
typedef __attribute__((ext_vector_type(8))) __bf16 bf16x8;
typedef __attribute__((ext_vector_type(4))) float f32x4;

__device__ __forceinline__ float toF(bf16 v) { return __bfloat162float(v); }

// dual-dtype load: dt=1 -> underlying memory is fp32; dt=0 -> bf16
__device__ __forceinline__ float ldf(const void* p, size_t i, int dt) {
  return dt ? ((const float*)p)[i] : __bfloat162float(((const bf16*)p)[i]);
}
__device__ __forceinline__ ushort toBF(float f) {
  union { bf16 b; ushort u; } cv; cv.b = __float2bfloat16(f); return cv.u;
}

// ---------------- dtype detection ----------------
__global__ void detect_dtype(const void* x, int n, int* flag) {
  __shared__ int s;
  if (threadIdx.x == 0) s = 0;
  __syncthreads();
  const bf16* xb = (const bf16*)x;
  int bad = 0;
  for (int i = threadIdx.x; i < n; i += 256) {
    float v = __bfloat162float(xb[i]);
    if (!(fabsf(v) < 1e6f)) bad = 1;
  }
  if (bad) atomicOr(&s, 1);
  __syncthreads();
  if (threadIdx.x == 0) flag[0] = s;
}

// ---------------- zero-init (replaces two hipMemsetAsync dispatches) ----------------
__global__ __launch_bounds__(256) void init_zero(int* __restrict__ cnt, float* __restrict__ pooled,
                                                 int N, int P) {
  int i = blockIdx.x * 256 + threadIdx.x;
  if (i < N) cnt[i] = 0;
  else if (i < N + P) pooled[i - N] = 0.f;
}

// ---------------- CSR build (real edges only; self-loops analytic in agg) -------------
__global__ void count_rank(const int* __restrict__ ei, int E,
                           int* __restrict__ cnt, int* __restrict__ rank) {
  int e = blockIdx.x * blockDim.x + threadIdx.x;
  if (e >= E) return;
  int d = ei[E + e];
  rank[e] = atomicAdd(&cnt[d], 1);
}

__global__ __launch_bounds__(256) void scan_reduce(const int* __restrict__ cnt, int n, int* __restrict__ csum) {
  int base = blockIdx.x * 1024;
  int t = threadIdx.x;
  int s = 0;
#pragma unroll
  for (int j = 0; j < 4; j++) {
    int i = base + t * 4 + j;
    if (i < n) s += cnt[i];
  }
#pragma unroll
  for (int off = 32; off > 0; off >>= 1) s += __shfl_down(s, off, 64);
  __shared__ int ws[4];
  if ((t & 63) == 0) ws[t >> 6] = s;
  __syncthreads();
  if (t == 0) csum[blockIdx.x] = ws[0] + ws[1] + ws[2] + ws[3];
}

__global__ __launch_bounds__(256) void scan_top(int* __restrict__ csum, int nb, int* __restrict__ rowstart, int n) {
  __shared__ int sc[256];
  int t = threadIdx.x;
  int v0 = (t < nb) ? csum[t] : 0;
  sc[t] = v0;
  for (int off = 1; off < 256; off <<= 1) {
    __syncthreads();
    int v = (t >= off) ? sc[t - off] : 0;
    __syncthreads();
    sc[t] += v;
  }
  __syncthreads();
  if (t < nb) csum[t] = sc[t] - v0;  // exclusive
  if (t == 0) rowstart[n] = sc[255]; // total
}

__global__ __launch_bounds__(256) void scan_down(const int* __restrict__ cnt, int n,
                                                 const int* __restrict__ csum,
                                                 int* __restrict__ rowstart) {
  int base = blockIdx.x * 1024;
  int t = threadIdx.x, lane = t & 63, w = t >> 6;
  int v[4];
#pragma unroll
  for (int j = 0; j < 4; j++) {
    int i = base + t * 4 + j;
    v[j] = (i < n) ? cnt[i] : 0;
  }
  int s1 = v[0], s2 = s1 + v[1], s3 = s2 + v[2], s4 = s3 + v[3];
  int x = s4;
#pragma unroll
  for (int off = 1; off < 64; off <<= 1) {
    int y = __shfl_up(x, off, 64);
    if (lane >= off) x += y;
  }
  int texcl = x - s4;
  __shared__ int ws[4];
  if (lane == 63) ws[w] = x;
  __syncthreads();
  int woff = 0;
  for (int i = 0; i < 4; i++) if (i < w) woff += ws[i];
  int b0 = csum[blockIdx.x] + woff + texcl;
  int e0 = b0, e1 = b0 + s1, e2 = b0 + s2, e3 = b0 + s3;
  int i0 = base + t * 4;
  if (i0 + 0 < n) rowstart[i0 + 0] = e0;
  if (i0 + 1 < n) rowstart[i0 + 1] = e1;
  if (i0 + 2 < n) rowstart[i0 + 2] = e2;
  if (i0 + 3 < n) rowstart[i0 + 3] = e3;
}

__global__ void scatter2(const int* __restrict__ ei, int E,
                         const int* __restrict__ rowstart, const int* __restrict__ rank,
                         int* __restrict__ adj) {
  int e = blockIdx.x * blockDim.x + threadIdx.x;
  if (e >= E) return;
  int s = ei[e], d = ei[E + e];
  adj[rowstart[d] + rank[e]] = s;
}

// ---------------- consolidated parameter pack: Wt0, Wt1, head fp32 table ----------------
// Wt2 layout for direct MFMA frag loads: Wt2[k/8][col][k%8], zero-padded k in [K,Kpad).
__global__ __launch_bounds__(256) void pack_params(
    const void* __restrict__ W0, const void* __restrict__ W1,
    const void* __restrict__ Wn, const void* __restrict__ Wr,
    const void* __restrict__ bn, const void* __restrict__ br,
    const void* __restrict__ Wc, const void* __restrict__ bc,
    ushort* __restrict__ Wt0, ushort* __restrict__ Wt1, float* __restrict__ HW,
    int IN, int Kpad0, const int* __restrict__ dtflag) {
  int dt = dtflag[0];
  int b = blockIdx.x, t = threadIdx.x;
  if (b < 128) {
    // Wt0 column b, K=IN padded to Kpad0
    for (int k = t; k < Kpad0; k += 256) {
      float v = (k < IN) ? ldf(W0, (size_t)k * 128 + b, dt) : 0.f;
      Wt0[((size_t)(k >> 3) * 128 + b) * 8 + (k & 7)] = toBF(v);
    }
  } else if (b < 256) {
    // Wt1 column b-128, K=128
    int c = b - 128;
    if (t < 128) {
      int k = t;
      Wt1[((size_t)(k >> 3) * 128 + c) * 8 + (k & 7)] = toBF(ldf(W1, (size_t)k * 128 + c, dt));
    }
  } else {
    // head fp32 pack: [Wn | Wr | bn | br | Wc | bc]
    int i = (b - 256) * 256 + t;
    int s0 = IN * 128, s1 = s0 + 128 * 128, s2 = s1 + 128, s3 = s2 + 128, s4 = s3 + 256, s5 = s4 + 1;
    if (i >= s5) return;
    float v;
    if (i < s0) v = ldf(Wn, i, dt);
    else if (i < s1) v = ldf(Wr, i - s0, dt);
    else if (i < s2) v = ldf(bn, i - s1, dt);
    else if (i < s3) v = ldf(br, i - s2, dt);
    else if (i < s4) v = ldf(Wc, i - s3, dt);
    else v = ldf(bc, 0, dt);
    HW[i] = v;
  }
}

// ---------------- MFMA GEMM v4: LDS A-panel, fused fp32->bf16 staging ----------------
// C[nrows,128] = A[nrows,K] @ W[K,128]. LDS panel rows are bf16, RB bytes each.
// CVT=true: when dtflag says fp32, stage-convert from fp32 source directly (no pre-pack pass).
// One barrier; K-loop reads A-frags from LDS, W frags from global (L2-resident).
// K-tail cols covered by Wt2 zero-pad (garbage-A x zero-W = 0; A bytes always finite bf16).
template <int RB, bool ALIGN16, bool CVT>
__global__ __launch_bounds__(256) void mfma_gemm4(const void* __restrict__ A0,
                                                  const ushort* __restrict__ Wt2,
                                                  bf16* __restrict__ C,
                                                  float2* __restrict__ as2, float2* __restrict__ ad2,
                                                  const void* __restrict__ aS, const void* __restrict__ aD,
                                                  int nrows, int K, const int* __restrict__ dtflag) {
  __shared__ __align__(16) unsigned char panel[64 * RB + 64];  // +64 pad (zeroed) for tail reads
  int dtg = dtflag[0];
  int tid = threadIdx.x;
  int row0 = blockIdx.x * 64;

  if (CVT && dtg) {
    // ---- stage + convert: contiguous fp32 stream -> bf16 panel ----
    const float* Af = (const float*)A0 + (size_t)row0 * K;
    size_t availf = (size_t)nrows * K - (size_t)row0 * K;
    size_t pf = availf < (size_t)(64 * K) ? availf : (size_t)(64 * K);
    int nch = (int)(pf >> 2);
    for (int c = tid; c < nch; c += 256) {
      float4 v = ((const float4*)Af)[c];
      uint2 o;
      o.x = (uint)toBF(v.x) | ((uint)toBF(v.y) << 16);
      o.y = (uint)toBF(v.z) | ((uint)toBF(v.w) << 16);
      *(uint2*)&panel[(size_t)c << 3] = o;
    }
    // scalar fixup for non-multiple-of-4 float tail
    for (int f = (nch << 2) + tid; f < (int)pf; f += 256)
      ((ushort*)panel)[f] = toBF(Af[f]);
    // zero everything past valid elems (absent rows + pad)
    for (int u2 = (int)pf + tid; u2 < (64 * RB + 64) / 2; u2 += 256)
      ((ushort*)panel)[u2] = 0;
  } else {
    // ---- stage panel: contiguous bf16 bytes, perfectly coalesced ----
    const unsigned char* A = (const unsigned char*)A0;
    size_t gbase = (size_t)row0 * RB;
    size_t avail = (size_t)nrows * RB - gbase;
    size_t pbytes = avail < (size_t)(64 * RB) ? avail : (size_t)(64 * RB);
    int nchunk = (int)(pbytes >> 4);
    const uint4* gsrc = (const uint4*)(A + gbase);
    for (int c = tid; c < nchunk; c += 256)
      *(uint4*)&panel[(size_t)c << 4] = gsrc[c];
    for (int b = (nchunk << 4) + tid * 4; b < (int)pbytes; b += 1024)
      *(uint*)&panel[b] = *(const uint*)(A + gbase + b);
    for (int b = (int)((pbytes + 3) & ~3ull) + tid * 4; b < 64 * RB + 64; b += 1024)
      *(uint*)&panel[b] = 0u;
  }
  __syncthreads();

  int wave = tid >> 6, lane = tid & 63;
  int m = lane & 15, q = lane >> 4;
  int lrow = wave * 16 + m;
  const unsigned char* prow = &panel[(size_t)lrow * RB];

  f32x4 acc[8];
#pragma unroll
  for (int ct = 0; ct < 8; ct++) acc[ct] = (f32x4){0.f, 0.f, 0.f, 0.f};

  const ushort* wq = Wt2 + (size_t)q * 1024 + (size_t)m * 8;
  int niter = (K + 31) >> 5;
  for (int it = 0; it < niter; it++) {
    bf16x8 av;
    if (ALIGN16) {
      av = *(const bf16x8*)(prow + it * 64 + q * 16);
    } else {
      uint u[4];
#pragma unroll
      for (int j = 0; j < 4; j++) u[j] = *(const uint*)(prow + it * 64 + q * 16 + j * 4);
      __builtin_memcpy(&av, u, 16);
    }
    const ushort* wk = wq + (size_t)it * 4096;
    bf16x8 wv[8];
#pragma unroll
    for (int ct = 0; ct < 8; ct++) wv[ct] = *(const bf16x8*)(wk + ct * 128);
#pragma unroll
    for (int ct = 0; ct < 8; ct++)
      acc[ct] = __builtin_amdgcn_mfma_f32_16x16x32_bf16(av, wv[ct], acc[ct], 0, 0, 0);
  }

  // ---- C writeback (C/D: col=lane&15, row=q*4+r) ----
#pragma unroll
  for (int ct = 0; ct < 8; ct++) {
#pragma unroll
    for (int r = 0; r < 4; r++) {
      int grow = row0 + wave * 16 + q * 4 + r;
      if (grow < nrows) C[(size_t)grow * 128 + ct * 16 + m] = __float2bfloat16(acc[ct][r]);
    }
  }

  // ---- fused attention logits ----
  float aSv[8], aDv[8];
#pragma unroll
  for (int ct = 0; ct < 8; ct++) {
    aSv[ct] = ldf(aS, ct * 16 + m, dtg);
    aDv[ct] = ldf(aD, ct * 16 + m, dtg);
  }
#pragma unroll
  for (int r = 0; r < 4; r++) {
    float s0 = 0.f, s1 = 0.f, d0 = 0.f, d1 = 0.f;
#pragma unroll
    for (int ct = 0; ct < 4; ct++) {
      float v = acc[ct][r];
      s0 += v * aSv[ct]; d0 += v * aDv[ct];
    }
#pragma unroll
    for (int ct = 4; ct < 8; ct++) {
      float v = acc[ct][r];
      s1 += v * aSv[ct]; d1 += v * aDv[ct];
    }
#pragma unroll
    for (int off = 1; off < 16; off <<= 1) {
      s0 += __shfl_xor(s0, off, 64);
      s1 += __shfl_xor(s1, off, 64);
      d0 += __shfl_xor(d0, off, 64);
      d1 += __shfl_xor(d1, off, 64);
    }
    int grow = row0 + wave * 16 + q * 4 + r;
    if (m == 0 && grow < nrows) {
      as2[grow] = make_float2(s0, s1);
      ad2[grow] = make_float2(d0, d1);
    }
  }
}

// ---------------- generic fallback GEMM (any K / dtype) -------
__global__ __launch_bounds__(256) void mfma_gemm_gen(const void* __restrict__ A, const ushort* __restrict__ Wt2,
                                                     bf16* __restrict__ C,
                                                     float2* __restrict__ as2, float2* __restrict__ ad2,
                                                     const void* __restrict__ aS, const void* __restrict__ aD,
                                                     int nrows, int K, const int* __restrict__ dtflag) {
  int dtg = dtflag[0];
  int tid = threadIdx.x;
  int wave = tid >> 6, lane = tid & 63;
  int m = lane & 15, q = lane >> 4;
  int row0 = blockIdx.x * 64;
  int rowA = row0 + wave * 16 + m;
  int rA = rowA < nrows ? rowA : nrows - 1;

  f32x4 acc[8];
#pragma unroll
  for (int ct = 0; ct < 8; ct++) acc[ct] = (f32x4){0.f, 0.f, 0.f, 0.f};

  const ushort* wq = Wt2 + (size_t)q * 1024 + (size_t)m * 8;
  int niter = (K + 31) >> 5;
  for (int it = 0; it < niter; it++) {
    ushort u[8];
#pragma unroll
    for (int j = 0; j < 8; j++) {
      int k = it * 32 + q * 8 + j;
      u[j] = (k < K) ? toBF(ldf(A, (size_t)rA * K + k, dtg)) : (ushort)0;
    }
    bf16x8 av;
    __builtin_memcpy(&av, u, 16);
    const ushort* wk = wq + (size_t)it * 4096;
    bf16x8 wv[8];
#pragma unroll
    for (int ct = 0; ct < 8; ct++) wv[ct] = *(const bf16x8*)(wk + ct * 128);
#pragma unroll
    for (int ct = 0; ct < 8; ct++)
      acc[ct] = __builtin_amdgcn_mfma_f32_16x16x32_bf16(av, wv[ct], acc[ct], 0, 0, 0);
  }
#pragma unroll
  for (int ct = 0; ct < 8; ct++) {
#pragma unroll
    for (int r = 0; r < 4; r++) {
      int grow = row0 + wave * 16 + q * 4 + r;
      if (grow < nrows) C[(size_t)grow * 128 + ct * 16 + m] = __float2bfloat16(acc[ct][r]);
    }
  }
  float aSv[8], aDv[8];
#pragma unroll
  for (int ct = 0; ct < 8; ct++) {
    aSv[ct] = ldf(aS, ct * 16 + m, dtg);
    aDv[ct] = ldf(aD, ct * 16 + m, dtg);
  }
#pragma unroll
  for (int r = 0; r < 4; r++) {
    float s0 = 0.f, s1 = 0.f, d0 = 0.f, d1 = 0.f;
#pragma unroll
    for (int ct = 0; ct < 4; ct++) { float v = acc[ct][r]; s0 += v * aSv[ct]; d0 += v * aDv[ct]; }
#pragma unroll
    for (int ct = 4; ct < 8; ct++) { float v = acc[ct][r]; s1 += v * aSv[ct]; d1 += v * aDv[ct]; }
#pragma unroll
    for (int off = 1; off < 16; off <<= 1) {
      s0 += __shfl_xor(s0, off, 64);
      s1 += __shfl_xor(s1, off, 64);
      d0 += __shfl_xor(d0, off, 64);
      d1 += __shfl_xor(d1, off, 64);
    }
    int grow = row0 + wave * 16 + q * 4 + r;
    if (m == 0 && grow < nrows) {
      as2[grow] = make_float2(s0, s1);
      ad2[grow] = make_float2(d0, d1);
    }
  }
}

// ---------------- GAT aggregate v5: 16-deep gather pipeline, deferred den-reduce ------
// POOL=true (layer 1): h is consumed only by mean-pool, so skip the h write entirely and
// accumulate into pooled[] directly. Per-block 4-node LDS pre-reduction (batch is sorted,
// so the 4 nodes of a block share a graph except at ~1% of blocks) keeps atomics ~1.6M.
#define GCAP 64
template <bool POOL>
__global__ __launch_bounds__(256) void gat_agg5(const bf16* __restrict__ xw,
                                                const float2* __restrict__ as2, const float2* __restrict__ ad2,
                                                const int* __restrict__ rowstart, const int* __restrict__ adj,
                                                const void* __restrict__ bias, bf16* __restrict__ out,
                                                float* __restrict__ pooled, const int* __restrict__ batch,
                                                int N, const int* __restrict__ dtflag) {
  __shared__ float2 sW[4][GCAP];
  __shared__ int sS[4][GCAP];
  int dt = dtflag[0];
  int wslot = threadIdx.x >> 6;
  int lane = threadIdx.x & 63;
  int n = (blockIdx.x * blockDim.x + threadIdx.x) >> 6;
  bool act = n < N;
  int r0 = 0, r1 = 0;
  float2 adv = make_float2(0.f, 0.f), asn = make_float2(0.f, 0.f);
  if (act) { r0 = rowstart[n]; r1 = rowstart[n + 1]; adv = ad2[n]; asn = as2[n]; }
  int deg = r1 - r0;

  float es0 = asn.x + adv.x; es0 = es0 > 0.f ? es0 : 0.2f * es0;
  float es1 = asn.y + adv.y; es1 = es1 > 0.f ? es1 : 0.2f * es1;
  float ws0 = __expf(fminf(es0, 60.f)), ws1 = __expf(fminf(es1, 60.f));

  // phase 1: per-edge weights into LDS (one edge per lane) + per-lane den partials.
  float den0, den1;
  {
    bool v = act && lane < deg;
    int s = v ? adj[r0 + lane] : 0;
    float w0 = 0.f, w1 = 0.f;
    if (v) {
      float2 asv = as2[s];
      float e0 = asv.x + adv.x; e0 = e0 > 0.f ? e0 : 0.2f * e0;
      float e1 = asv.y + adv.y; e1 = e1 > 0.f ? e1 : 0.2f * e1;
      w0 = __expf(fminf(e0, 60.f)); w1 = __expf(fminf(e1, 60.f));
    }
    sW[wslot][lane] = make_float2(w0, w1);
    sS[wslot][lane] = s;
    den0 = w0; den1 = w1;
  }
  for (int i = r0 + GCAP + lane; i < r1; i += 64) {
    int s = adj[i];
    float2 asv = as2[s];
    float e0 = asv.x + adv.x; e0 = e0 > 0.f ? e0 : 0.2f * e0;
    float e1 = asv.y + adv.y; e1 = e1 > 0.f ? e1 : 0.2f * e1;
    den0 += __expf(fminf(e0, 60.f)); den1 += __expf(fminf(e1, 60.f));
  }

  // phase 2: 16-deep batched row gathers. Slots [cap,capR) hold w=0,s=0 (written by all
  // 64 lanes above), so the dummy gathers hit the hot row 0 and contribute exactly 0.
  // den cross-lane reduction is deferred past this loop (inv needed only at the end).
  const uint* xw32 = (const uint*)xw;
  float wsS = (lane < 32) ? ws0 : ws1;
  uint pvs = act ? xw32[((size_t)n << 6) + lane] : 0;
  float a0 = wsS * __uint_as_float(pvs << 16);
  float a1 = wsS * __uint_as_float(pvs & 0xffff0000u);
  int cap = deg < GCAP ? deg : GCAP;
  int capR = (cap + 15) & ~15;   // wave-uniform; <=64 since GCAP=64
  for (int i = 0; i < capR; i += 16) {
    uint pv[16]; float wsv[16];
#pragma unroll
    for (int j = 0; j < 16; j++) {
      float2 wv = sW[wslot][i + j];
      int s = sS[wslot][i + j];
      wsv[j] = (lane < 32) ? wv.x : wv.y;
      pv[j] = xw32[((size_t)s << 6) + lane];
    }
#pragma unroll
    for (int j = 0; j < 16; j++) {
      a0 += wsv[j] * __uint_as_float(pv[j] << 16);
      a1 += wsv[j] * __uint_as_float(pv[j] & 0xffff0000u);
    }
  }
  for (int i = GCAP; i < deg; i++) {
    int s = adj[r0 + i];
    float2 asv = as2[s];
    float e0 = asv.x + adv.x; e0 = e0 > 0.f ? e0 : 0.2f * e0;
    float e1 = asv.y + adv.y; e1 = e1 > 0.f ? e1 : 0.2f * e1;
    float w0 = __expf(fminf(e0, 60.f)), w1 = __expf(fminf(e1, 60.f));
    uint pv = xw32[((size_t)s << 6) + lane];
    float ws = (lane < 32) ? w0 : w1;
    a0 += ws * __uint_as_float(pv << 16);
    a1 += ws * __uint_as_float(pv & 0xffff0000u);
  }

  // deferred den reduction + self term
#pragma unroll
  for (int off = 32; off > 0; off >>= 1) {
    den0 += __shfl_xor(den0, off, 64);
    den1 += __shfl_xor(den1, off, 64);
  }
  den0 += ws0; den1 += ws1;
  float inv0 = 1.f / (den0 + 1e-16f), inv1 = 1.f / (den1 + 1e-16f);

  int c0 = 2 * lane;
  float invs = (lane < 32) ? inv0 : inv1;
  float o0 = a0 * invs + ldf(bias, c0, dt);
  float o1 = a1 * invs + ldf(bias, c0 + 1, dt);
  o0 = o0 > 0.f ? o0 : 0.f;
  o1 = o1 > 0.f ? o1 : 0.f;

  if constexpr (POOL) {
    __shared__ float spool[4][128];
    __shared__ int sg[4];
    int g = act ? batch[n] : -1;
    if (lane == 0) sg[wslot] = g;
    spool[wslot][c0] = act ? o0 : 0.f;
    spool[wslot][c0 + 1] = act ? o1 : 0.f;
    __syncthreads();
    bool uni = sg[0] >= 0 && sg[0] == sg[1] && sg[1] == sg[2] && sg[2] == sg[3];
    if (uni) {
      if (threadIdx.x < 128) {
        float s = spool[0][threadIdx.x] + spool[1][threadIdx.x] +
                  spool[2][threadIdx.x] + spool[3][threadIdx.x];
        atomicAdd(&pooled[(size_t)sg[0] * 128 + threadIdx.x], s);
      }
    } else if (act) {
      atomicAdd(&pooled[(size_t)g * 128 + c0], o0);
      atomicAdd(&pooled[(size_t)g * 128 + c0 + 1], o1);
    }
  } else {
    if (act) {
      uint pk = (uint)toBF(o0) | ((uint)toBF(o1) << 16);
      ((uint*)out)[(size_t)n * 64 + lane] = pk;
    }
  }
}

// ---------------- head v4: fp32-packed weights, no per-load dtype branch ----------------
__global__ __launch_bounds__(512) void head4_kernel(
    const float* __restrict__ pooled, const void* __restrict__ x, const int* __restrict__ batch,
    const float* __restrict__ HW, void* __restrict__ out, int N, int IN,
    const int* __restrict__ dtflag) {
  const float* Wn_f = HW;
  const float* Wr_f = HW + (size_t)IN * 128;
  const float* bn_f = Wr_f + 128 * 128;
  const float* br_f = bn_f + 128;
  const float* Wc_f = br_f + 128;
  const float* bc_f = Wc_f + 256;
  int dt = dtflag[0];
  int b = blockIdx.x;
  int tid = threadIdx.x;
  int t = tid & 127, g = tid >> 7;
  __shared__ int sr0, sr1;
  __shared__ float xs[512];
  __shared__ float pl[128];
  __shared__ float pn[4][128];
  __shared__ float pg[4][128];
  __shared__ float red[128];
  if (tid == 0) {
    int lo = 0, hi = N;
    while (lo < hi) { int mid = (lo + hi) >> 1; if (batch[mid] < b) lo = mid + 1; else hi = mid; }
    sr0 = lo;
  }
  if (tid == 1) {
    int lo = 0, hi = N, b1 = b + 1;
    while (lo < hi) { int mid = (lo + hi) >> 1; if (batch[mid] < b1) lo = mid + 1; else hi = mid; }
    sr1 = lo;
  }
  __syncthreads();
  int r0 = sr0;
  float inv_cnt = 1.f / (float)(sr1 - r0);
  if (tid < 128) pl[tid] = pooled[(size_t)b * 128 + tid] * inv_cnt;
  if (dt) {
    const float* xf = (const float*)x + (size_t)r0 * IN;
    for (int k = tid; k < IN; k += 512) xs[k] = xf[k];
  } else {
    const bf16* xb = (const bf16*)x + (size_t)r0 * IN;
    for (int k = tid; k < IN; k += 512) xs[k] = toF(xb[k]);
  }
  __syncthreads();

  float n0 = 0.f, n1 = 0.f, n2 = 0.f, n3 = 0.f;
  {
    int k = g;
    for (; k + 12 < IN; k += 16) {
      n0 += xs[k]      * Wn_f[(size_t)k * 128 + t];
      n1 += xs[k + 4]  * Wn_f[(size_t)(k + 4) * 128 + t];
      n2 += xs[k + 8]  * Wn_f[(size_t)(k + 8) * 128 + t];
      n3 += xs[k + 12] * Wn_f[(size_t)(k + 12) * 128 + t];
    }
    for (; k < IN; k += 4) n0 += xs[k] * Wn_f[(size_t)k * 128 + t];
  }
  float g0 = 0.f, g1 = 0.f;
  {
    int k = g;
    for (; k + 4 < 128; k += 8) {
      g0 += pl[k]     * Wr_f[(size_t)k * 128 + t];
      g1 += pl[k + 4] * Wr_f[(size_t)(k + 4) * 128 + t];
    }
    for (; k < 128; k += 4) g0 += pl[k] * Wr_f[(size_t)k * 128 + t];
  }
  pn[g][t] = (n0 + n1) + (n2 + n3);
  pg[g][t] = g0 + g1;
  __syncthreads();
  if (tid < 128) {
    float nw = pn[0][t] + pn[1][t] + pn[2][t] + pn[3][t] + bn_f[t];
    nw = nw > 0.f ? nw : 0.f;
    float gg = pg[0][t] + pg[1][t] + pg[2][t] + pg[3][t] + br_f[t];
    gg = gg > 0.f ? gg : 0.f;
    red[t] = gg * Wc_f[t] + nw * Wc_f[128 + t];
  }
  __syncthreads();
  for (int s = 64; s > 0; s >>= 1) {
    if (tid < s) red[tid] += red[tid + s];
    __syncthreads();
  }
  if (tid == 0) {
    float z = red[0] + bc_f[0];
    float r = 1.f / (1.f + __expf(-z));
    if (dt) ((float*)out)[b] = r;
    else ((bf16*)out)[b] = __float2bfloat16(r);
  }
}

extern "C" void kernel_launch(void* const* d_in, const int* in_sizes, int n_in,
                              void* d_out, int out_size, void* d_ws, size_t ws_size,
                              hipStream_t stream) {
  const void* x   = d_in[0];
  const void* W0  = d_in[1];
  const void* aS0 = d_in[2];
  const void* aD0 = d_in[3];
  const void* b0  = d_in[4];
  const void* W1  = d_in[5];
  const void* aS1 = d_in[6];
  const void* aD1 = d_in[7];
  const void* b1  = d_in[8];
  const void* Wn  = d_in[9];
  const void* bn  = d_in[10];
  const void* Wr  = d_in[11];
  const void* br  = d_in[12];
  const void* Wc  = d_in[13];
  const void* bc  = d_in[14];
  const int* ei    = (const int*)d_in[15];
  const int* batch = (const int*)d_in[16];

  const int N = in_sizes[16];
  const int IN = in_sizes[0] / N;
  const int E = in_sizes[15] / 2;
  const int B = out_size;
  const int Kpad0 = (IN + 31) / 32 * 32;   // 320
  const int hw_elems = IN * 128 + 128 * 128 + 128 + 128 + 256 + 1;

  char* w = (char*)d_ws;
  size_t off = 0;
  auto alloc = [&](size_t bytes) { void* p = w + off; off += (bytes + 255) / 256 * 256; return p; };
  int* flag      = (int*)alloc(256);
  bf16* bufA     = (bf16*)alloc((size_t)N * 128 * 2);
  bf16* bufB     = (bf16*)alloc((size_t)N * 128 * 2);
  float2* as2    = (float2*)alloc((size_t)N * 8);
  float2* ad2    = (float2*)alloc((size_t)N * 8);
  int* cnt       = (int*)alloc((size_t)N * 4);
  int* rowstart  = (int*)alloc((size_t)(N + 1) * 4);
  int* rank      = (int*)alloc((size_t)E * 4);
  int* adj       = (int*)alloc((size_t)E * 4);
  int* csum      = (int*)alloc(1024);
  ushort* Wt0    = (ushort*)alloc((size_t)128 * Kpad0 * 2);
  ushort* Wt1    = (ushort*)alloc((size_t)128 * 128 * 2);
  float* pooled  = (float*)alloc((size_t)B * 128 * 4);
  float* HW      = (float*)alloc((size_t)hw_elems * 4);

  int ndet = in_sizes[0] < 4096 ? in_sizes[0] : 4096;
  detect_dtype<<<1, 256, 0, stream>>>(x, ndet, flag);

  // zero cnt + pooled in one dispatch (replaces two hipMemsetAsync)
  int zn = N + B * 128;
  init_zero<<<(zn + 255) / 256, 256, 0, stream>>>(cnt, pooled, N, B * 128);

  const int tb = 256;
  count_rank<<<(E + tb - 1) / tb, tb, 0, stream>>>(ei, E, cnt, rank);
  int nb = (N + 1023) / 1024;
  scan_reduce<<<nb, 256, 0, stream>>>(cnt, N, csum);
  scan_top<<<1, 256, 0, stream>>>(csum, nb, rowstart, N);
  scan_down<<<nb, 256, 0, stream>>>(cnt, N, csum, rowstart);
  scatter2<<<(E + tb - 1) / tb, tb, 0, stream>>>(ei, E, rowstart, rank, adj);

  // one consolidated parameter-pack dispatch: Wt0 (128 blocks) + Wt1 (128) + head table
  int pgrid_params = 256 + (hw_elems + 255) / 256;
  pack_params<<<pgrid_params, 256, 0, stream>>>(W0, W1, Wn, Wr, bn, br, Wc, bc,
                                                Wt0, Wt1, HW, IN, Kpad0, flag);

  int ggrid = (N + 63) / 64;
  int wgrid = ((N * 64) + 255) / 256;

  // Layer 0: fast panel path for the known shape (IN=310), fp32->bf16 conversion fused
  // into LDS staging (no separate pack pass); generic fallback otherwise
  if (IN == 310) {
    mfma_gemm4<620, false, true><<<ggrid, 256, 0, stream>>>(x, Wt0, bufA, as2, ad2, aS0, aD0, N, IN, flag);
  } else {
    mfma_gemm_gen<<<ggrid, 256, 0, stream>>>(x, Wt0, bufA, as2, ad2, aS0, aD0, N, IN, flag);
  }
  gat_agg5<false><<<wgrid, 256, 0, stream>>>(bufA, as2, ad2, rowstart, adj, b0, bufB,
                                             nullptr, nullptr, N, flag);

  // Layer 1: bf16 buffer, 256B rows, 16B-aligned; pooling fused into the aggregate
  mfma_gemm4<256, true, false><<<ggrid, 256, 0, stream>>>(bufB, Wt1, bufA, as2, ad2, aS1, aD1, N, 128, flag);
  gat_agg5<true><<<wgrid, 256, 0, stream>>>(bufA, as2, ad2, rowstart, adj, b1, nullptr,
                                            pooled, batch, N, flag);

  // Head
  head4_kernel<<<B, 512, 0, stream>>>(pooled, x, batch, HW, (void*)d_out, N, IN, flag);
}

// Round 3
// 313.717 us; speedup vs baseline: 1.1408x; 1.0308x over previous
//
#include <hip/hip_runtime.h>
#include <hip/hip_bf16.h>

typedef __hip_bfloat16 bf16;
typedef __attribute__((ext_vector_type(8))) __bf16 bf16x8;
typedef __attribute__((ext_vector_type(4))) float f32x4;

__device__ __forceinline__ float toF(bf16 v) { return __bfloat162float(v); }

// dual-dtype load: dt=1 -> underlying memory is fp32; dt=0 -> bf16
__device__ __forceinline__ float ldf(const void* p, size_t i, int dt) {
  return dt ? ((const float*)p)[i] : __bfloat162float(((const bf16*)p)[i]);
}
__device__ __forceinline__ ushort toBF(float f) {
  union { bf16 b; ushort u; } cv; cv.b = __float2bfloat16(f); return cv.u;
}

// ---------------- dtype detection ----------------
__global__ void detect_dtype(const void* x, int n, int* flag) {
  __shared__ int s;
  if (threadIdx.x == 0) s = 0;
  __syncthreads();
  const bf16* xb = (const bf16*)x;
  int bad = 0;
  for (int i = threadIdx.x; i < n; i += 256) {
    float v = __bfloat162float(xb[i]);
    if (!(fabsf(v) < 1e6f)) bad = 1;
  }
  if (bad) atomicOr(&s, 1);
  __syncthreads();
  if (threadIdx.x == 0) flag[0] = s;
}

// ---------------- zero-init (replaces two hipMemsetAsync dispatches) ----------------
__global__ __launch_bounds__(256) void init_zero(int* __restrict__ cnt, float* __restrict__ pooled,
                                                 int N, int P) {
  int i = blockIdx.x * 256 + threadIdx.x;
  if (i < N) cnt[i] = 0;
  else if (i < N + P) pooled[i - N] = 0.f;
}

// ---------------- CSR build (real edges only; self-loops analytic in agg) -------------
__global__ void count_rank(const int* __restrict__ ei, int E,
                           int* __restrict__ cnt, int* __restrict__ rank) {
  int e = blockIdx.x * blockDim.x + threadIdx.x;
  if (e >= E) return;
  int d = ei[E + e];
  rank[e] = atomicAdd(&cnt[d], 1);
}

__global__ __launch_bounds__(256) void scan_reduce(const int* __restrict__ cnt, int n, int* __restrict__ csum) {
  int base = blockIdx.x * 1024;
  int t = threadIdx.x;
  int s = 0;
#pragma unroll
  for (int j = 0; j < 4; j++) {
    int i = base + t * 4 + j;
    if (i < n) s += cnt[i];
  }
#pragma unroll
  for (int off = 32; off > 0; off >>= 1) s += __shfl_down(s, off, 64);
  __shared__ int ws[4];
  if ((t & 63) == 0) ws[t >> 6] = s;
  __syncthreads();
  if (t == 0) csum[blockIdx.x] = ws[0] + ws[1] + ws[2] + ws[3];
}

__global__ __launch_bounds__(256) void scan_top(int* __restrict__ csum, int nb, int* __restrict__ rowstart, int n) {
  __shared__ int sc[256];
  int t = threadIdx.x;
  int v0 = (t < nb) ? csum[t] : 0;
  sc[t] = v0;
  for (int off = 1; off < 256; off <<= 1) {
    __syncthreads();
    int v = (t >= off) ? sc[t - off] : 0;
    __syncthreads();
    sc[t] += v;
  }
  __syncthreads();
  if (t < nb) csum[t] = sc[t] - v0;  // exclusive
  if (t == 0) rowstart[n] = sc[255]; // total
}

__global__ __launch_bounds__(256) void scan_down(const int* __restrict__ cnt, int n,
                                                 const int* __restrict__ csum,
                                                 int* __restrict__ rowstart) {
  int base = blockIdx.x * 1024;
  int t = threadIdx.x, lane = t & 63, w = t >> 6;
  int v[4];
#pragma unroll
  for (int j = 0; j < 4; j++) {
    int i = base + t * 4 + j;
    v[j] = (i < n) ? cnt[i] : 0;
  }
  int s1 = v[0], s2 = s1 + v[1], s3 = s2 + v[2], s4 = s3 + v[3];
  int x = s4;
#pragma unroll
  for (int off = 1; off < 64; off <<= 1) {
    int y = __shfl_up(x, off, 64);
    if (lane >= off) x += y;
  }
  int texcl = x - s4;
  __shared__ int ws[4];
  if (lane == 63) ws[w] = x;
  __syncthreads();
  int woff = 0;
  for (int i = 0; i < 4; i++) if (i < w) woff += ws[i];
  int b0 = csum[blockIdx.x] + woff + texcl;
  int e0 = b0, e1 = b0 + s1, e2 = b0 + s2, e3 = b0 + s3;
  int i0 = base + t * 4;
  if (i0 + 0 < n) rowstart[i0 + 0] = e0;
  if (i0 + 1 < n) rowstart[i0 + 1] = e1;
  if (i0 + 2 < n) rowstart[i0 + 2] = e2;
  if (i0 + 3 < n) rowstart[i0 + 3] = e3;
}

__global__ void scatter2(const int* __restrict__ ei, int E,
                         const int* __restrict__ rowstart, const int* __restrict__ rank,
                         int* __restrict__ adj) {
  int e = blockIdx.x * blockDim.x + threadIdx.x;
  if (e >= E) return;
  int s = ei[e], d = ei[E + e];
  adj[rowstart[d] + rank[e]] = s;
}

// ---------------- consolidated parameter pack: Wt0, Wt1, head fp32 table ----------------
// Wt2 layout for direct MFMA frag loads: Wt2[k/8][col][k%8], zero-padded k in [K,Kpad).
__global__ __launch_bounds__(256) void pack_params(
    const void* __restrict__ W0, const void* __restrict__ W1,
    const void* __restrict__ Wn, const void* __restrict__ Wr,
    const void* __restrict__ bn, const void* __restrict__ br,
    const void* __restrict__ Wc, const void* __restrict__ bc,
    ushort* __restrict__ Wt0, ushort* __restrict__ Wt1, float* __restrict__ HW,
    int IN, int Kpad0, const int* __restrict__ dtflag) {
  int dt = dtflag[0];
  int b = blockIdx.x, t = threadIdx.x;
  if (b < 128) {
    // Wt0 column b, K=IN padded to Kpad0
    for (int k = t; k < Kpad0; k += 256) {
      float v = (k < IN) ? ldf(W0, (size_t)k * 128 + b, dt) : 0.f;
      Wt0[((size_t)(k >> 3) * 128 + b) * 8 + (k & 7)] = toBF(v);
    }
  } else if (b < 256) {
    // Wt1 column b-128, K=128
    int c = b - 128;
    if (t < 128) {
      int k = t;
      Wt1[((size_t)(k >> 3) * 128 + c) * 8 + (k & 7)] = toBF(ldf(W1, (size_t)k * 128 + c, dt));
    }
  } else {
    // head fp32 pack: [Wn | Wr | bn | br | Wc | bc]
    int i = (b - 256) * 256 + t;
    int s0 = IN * 128, s1 = s0 + 128 * 128, s2 = s1 + 128, s3 = s2 + 128, s4 = s3 + 256, s5 = s4 + 1;
    if (i >= s5) return;
    float v;
    if (i < s0) v = ldf(Wn, i, dt);
    else if (i < s1) v = ldf(Wr, i - s0, dt);
    else if (i < s2) v = ldf(bn, i - s1, dt);
    else if (i < s3) v = ldf(br, i - s2, dt);
    else if (i < s4) v = ldf(Wc, i - s3, dt);
    else v = ldf(bc, 0, dt);
    HW[i] = v;
  }
}

// ---------------- MFMA GEMM v4: LDS A-panel, fused fp32->bf16 staging ----------------
// C[nrows,128] = A[nrows,K] @ W[K,128]. LDS panel rows are bf16, RB bytes each.
// CVT=true: when dtflag says fp32, stage-convert from fp32 source directly (no pre-pack pass).
// One barrier; K-loop reads A-frags from LDS, W frags from global (L2-resident).
// K-tail cols covered by Wt2 zero-pad (garbage-A x zero-W = 0; A bytes always finite bf16).
template <int RB, bool ALIGN16, bool CVT>
__global__ __launch_bounds__(256) void mfma_gemm4(const void* __restrict__ A0,
                                                  const ushort* __restrict__ Wt2,
                                                  bf16* __restrict__ C,
                                                  float2* __restrict__ as2, float2* __restrict__ ad2,
                                                  const void* __restrict__ aS, const void* __restrict__ aD,
                                                  int nrows, int K, const int* __restrict__ dtflag) {
  __shared__ __align__(16) unsigned char panel[64 * RB + 64];  // +64 pad (zeroed) for tail reads
  int dtg = dtflag[0];
  int tid = threadIdx.x;
  int row0 = blockIdx.x * 64;

  if (CVT && dtg) {
    // ---- stage + convert: contiguous fp32 stream -> bf16 panel ----
    const float* Af = (const float*)A0 + (size_t)row0 * K;
    size_t availf = (size_t)nrows * K - (size_t)row0 * K;
    size_t pf = availf < (size_t)(64 * K) ? availf : (size_t)(64 * K);
    int nch = (int)(pf >> 2);
    for (int c = tid; c < nch; c += 256) {
      float4 v = ((const float4*)Af)[c];
      uint2 o;
      o.x = (uint)toBF(v.x) | ((uint)toBF(v.y) << 16);
      o.y = (uint)toBF(v.z) | ((uint)toBF(v.w) << 16);
      *(uint2*)&panel[(size_t)c << 3] = o;
    }
    // scalar fixup for non-multiple-of-4 float tail
    for (int f = (nch << 2) + tid; f < (int)pf; f += 256)
      ((ushort*)panel)[f] = toBF(Af[f]);
    // zero everything past valid elems (absent rows + pad)
    for (int u2 = (int)pf + tid; u2 < (64 * RB + 64) / 2; u2 += 256)
      ((ushort*)panel)[u2] = 0;
  } else {
    // ---- stage panel: contiguous bf16 bytes, perfectly coalesced ----
    const unsigned char* A = (const unsigned char*)A0;
    size_t gbase = (size_t)row0 * RB;
    size_t avail = (size_t)nrows * RB - gbase;
    size_t pbytes = avail < (size_t)(64 * RB) ? avail : (size_t)(64 * RB);
    int nchunk = (int)(pbytes >> 4);
    const uint4* gsrc = (const uint4*)(A + gbase);
    for (int c = tid; c < nchunk; c += 256)
      *(uint4*)&panel[(size_t)c << 4] = gsrc[c];
    for (int b = (nchunk << 4) + tid * 4; b < (int)pbytes; b += 1024)
      *(uint*)&panel[b] = *(const uint*)(A + gbase + b);
    for (int b = (int)((pbytes + 3) & ~3ull) + tid * 4; b < 64 * RB + 64; b += 1024)
      *(uint*)&panel[b] = 0u;
  }
  __syncthreads();

  int wave = tid >> 6, lane = tid & 63;
  int m = lane & 15, q = lane >> 4;
  int lrow = wave * 16 + m;
  const unsigned char* prow = &panel[(size_t)lrow * RB];

  f32x4 acc[8];
#pragma unroll
  for (int ct = 0; ct < 8; ct++) acc[ct] = (f32x4){0.f, 0.f, 0.f, 0.f};

  const ushort* wq = Wt2 + (size_t)q * 1024 + (size_t)m * 8;
  int niter = (K + 31) >> 5;
  for (int it = 0; it < niter; it++) {
    bf16x8 av;
    if (ALIGN16) {
      av = *(const bf16x8*)(prow + it * 64 + q * 16);
    } else {
      uint u[4];
#pragma unroll
      for (int j = 0; j < 4; j++) u[j] = *(const uint*)(prow + it * 64 + q * 16 + j * 4);
      __builtin_memcpy(&av, u, 16);
    }
    const ushort* wk = wq + (size_t)it * 4096;
    bf16x8 wv[8];
#pragma unroll
    for (int ct = 0; ct < 8; ct++) wv[ct] = *(const bf16x8*)(wk + ct * 128);
#pragma unroll
    for (int ct = 0; ct < 8; ct++)
      acc[ct] = __builtin_amdgcn_mfma_f32_16x16x32_bf16(av, wv[ct], acc[ct], 0, 0, 0);
  }

  // ---- C writeback (C/D: col=lane&15, row=q*4+r) ----
#pragma unroll
  for (int ct = 0; ct < 8; ct++) {
#pragma unroll
    for (int r = 0; r < 4; r++) {
      int grow = row0 + wave * 16 + q * 4 + r;
      if (grow < nrows) C[(size_t)grow * 128 + ct * 16 + m] = __float2bfloat16(acc[ct][r]);
    }
  }

  // ---- fused attention logits ----
  float aSv[8], aDv[8];
#pragma unroll
  for (int ct = 0; ct < 8; ct++) {
    aSv[ct] = ldf(aS, ct * 16 + m, dtg);
    aDv[ct] = ldf(aD, ct * 16 + m, dtg);
  }
#pragma unroll
  for (int r = 0; r < 4; r++) {
    float s0 = 0.f, s1 = 0.f, d0 = 0.f, d1 = 0.f;
#pragma unroll
    for (int ct = 0; ct < 4; ct++) {
      float v = acc[ct][r];
      s0 += v * aSv[ct]; d0 += v * aDv[ct];
    }
#pragma unroll
    for (int ct = 4; ct < 8; ct++) {
      float v = acc[ct][r];
      s1 += v * aSv[ct]; d1 += v * aDv[ct];
    }
#pragma unroll
    for (int off = 1; off < 16; off <<= 1) {
      s0 += __shfl_xor(s0, off, 64);
      s1 += __shfl_xor(s1, off, 64);
      d0 += __shfl_xor(d0, off, 64);
      d1 += __shfl_xor(d1, off, 64);
    }
    int grow = row0 + wave * 16 + q * 4 + r;
    if (m == 0 && grow < nrows) {
      as2[grow] = make_float2(s0, s1);
      ad2[grow] = make_float2(d0, d1);
    }
  }
}

// ---------------- generic fallback GEMM (any K / dtype) -------
__global__ __launch_bounds__(256) void mfma_gemm_gen(const void* __restrict__ A, const ushort* __restrict__ Wt2,
                                                     bf16* __restrict__ C,
                                                     float2* __restrict__ as2, float2* __restrict__ ad2,
                                                     const void* __restrict__ aS, const void* __restrict__ aD,
                                                     int nrows, int K, const int* __restrict__ dtflag) {
  int dtg = dtflag[0];
  int tid = threadIdx.x;
  int wave = tid >> 6, lane = tid & 63;
  int m = lane & 15, q = lane >> 4;
  int row0 = blockIdx.x * 64;
  int rowA = row0 + wave * 16 + m;
  int rA = rowA < nrows ? rowA : nrows - 1;

  f32x4 acc[8];
#pragma unroll
  for (int ct = 0; ct < 8; ct++) acc[ct] = (f32x4){0.f, 0.f, 0.f, 0.f};

  const ushort* wq = Wt2 + (size_t)q * 1024 + (size_t)m * 8;
  int niter = (K + 31) >> 5;
  for (int it = 0; it < niter; it++) {
    ushort u[8];
#pragma unroll
    for (int j = 0; j < 8; j++) {
      int k = it * 32 + q * 8 + j;
      u[j] = (k < K) ? toBF(ldf(A, (size_t)rA * K + k, dtg)) : (ushort)0;
    }
    bf16x8 av;
    __builtin_memcpy(&av, u, 16);
    const ushort* wk = wq + (size_t)it * 4096;
    bf16x8 wv[8];
#pragma unroll
    for (int ct = 0; ct < 8; ct++) wv[ct] = *(const bf16x8*)(wk + ct * 128);
#pragma unroll
    for (int ct = 0; ct < 8; ct++)
      acc[ct] = __builtin_amdgcn_mfma_f32_16x16x32_bf16(av, wv[ct], acc[ct], 0, 0, 0);
  }
#pragma unroll
  for (int ct = 0; ct < 8; ct++) {
#pragma unroll
    for (int r = 0; r < 4; r++) {
      int grow = row0 + wave * 16 + q * 4 + r;
      if (grow < nrows) C[(size_t)grow * 128 + ct * 16 + m] = __float2bfloat16(acc[ct][r]);
    }
  }
  float aSv[8], aDv[8];
#pragma unroll
  for (int ct = 0; ct < 8; ct++) {
    aSv[ct] = ldf(aS, ct * 16 + m, dtg);
    aDv[ct] = ldf(aD, ct * 16 + m, dtg);
  }
#pragma unroll
  for (int r = 0; r < 4; r++) {
    float s0 = 0.f, s1 = 0.f, d0 = 0.f, d1 = 0.f;
#pragma unroll
    for (int ct = 0; ct < 4; ct++) { float v = acc[ct][r]; s0 += v * aSv[ct]; d0 += v * aDv[ct]; }
#pragma unroll
    for (int ct = 4; ct < 8; ct++) { float v = acc[ct][r]; s1 += v * aSv[ct]; d1 += v * aDv[ct]; }
#pragma unroll
    for (int off = 1; off < 16; off <<= 1) {
      s0 += __shfl_xor(s0, off, 64);
      s1 += __shfl_xor(s1, off, 64);
      d0 += __shfl_xor(d0, off, 64);
      d1 += __shfl_xor(d1, off, 64);
    }
    int grow = row0 + wave * 16 + q * 4 + r;
    if (m == 0 && grow < nrows) {
      as2[grow] = make_float2(s0, s1);
      ad2[grow] = make_float2(d0, d1);
    }
  }
}

// ---------------- GAT aggregate v6 (round-1 structure): 8-deep gather, barrier-free ----
// One wave per node; per-edge weights cached in wave-private LDS slot; den reduced
// BEFORE the gather loop (round-1 proven ordering). Writes h to out.
#define GCAP 64
__global__ __launch_bounds__(256) void gat_agg6(const bf16* __restrict__ xw,
                                                const float2* __restrict__ as2, const float2* __restrict__ ad2,
                                                const int* __restrict__ rowstart, const int* __restrict__ adj,
                                                const void* __restrict__ bias, bf16* __restrict__ out, int N,
                                                const int* __restrict__ dtflag) {
  __shared__ float2 sW[4][GCAP];
  __shared__ int sS[4][GCAP];
  int dt = dtflag[0];
  int wslot = threadIdx.x >> 6;
  int lane = threadIdx.x & 63;
  int n = (blockIdx.x * blockDim.x + threadIdx.x) >> 6;
  bool act = n < N;
  int r0 = 0, r1 = 0;
  float2 adv = make_float2(0.f, 0.f), asn = make_float2(0.f, 0.f);
  if (act) { r0 = rowstart[n]; r1 = rowstart[n + 1]; adv = ad2[n]; asn = as2[n]; }
  int deg = r1 - r0;

  float es0 = asn.x + adv.x; es0 = es0 > 0.f ? es0 : 0.2f * es0;
  float es1 = asn.y + adv.y; es1 = es1 > 0.f ? es1 : 0.2f * es1;
  float ws0 = __expf(fminf(es0, 60.f)), ws1 = __expf(fminf(es1, 60.f));

  float den0, den1;
  {
    bool v = act && lane < deg;
    int s = v ? adj[r0 + lane] : 0;
    float w0 = 0.f, w1 = 0.f;
    if (v) {
      float2 asv = as2[s];
      float e0 = asv.x + adv.x; e0 = e0 > 0.f ? e0 : 0.2f * e0;
      float e1 = asv.y + adv.y; e1 = e1 > 0.f ? e1 : 0.2f * e1;
      w0 = __expf(fminf(e0, 60.f)); w1 = __expf(fminf(e1, 60.f));
    }
    sW[wslot][lane] = make_float2(w0, w1);
    sS[wslot][lane] = s;
    den0 = w0; den1 = w1;
  }
  for (int i = r0 + GCAP + lane; i < r1; i += 64) {
    int s = adj[i];
    float2 asv = as2[s];
    float e0 = asv.x + adv.x; e0 = e0 > 0.f ? e0 : 0.2f * e0;
    float e1 = asv.y + adv.y; e1 = e1 > 0.f ? e1 : 0.2f * e1;
    den0 += __expf(fminf(e0, 60.f)); den1 += __expf(fminf(e1, 60.f));
  }
#pragma unroll
  for (int off = 32; off > 0; off >>= 1) {
    den0 += __shfl_xor(den0, off, 64);
    den1 += __shfl_xor(den1, off, 64);
  }
  den0 += ws0; den1 += ws1;
  float inv0 = 1.f / (den0 + 1e-16f), inv1 = 1.f / (den1 + 1e-16f);

  const uint* xw32 = (const uint*)xw;
  float wsS = (lane < 32) ? ws0 : ws1;
  uint pvs = act ? xw32[((size_t)n << 6) + lane] : 0;
  float a0 = wsS * __uint_as_float(pvs << 16);
  float a1 = wsS * __uint_as_float(pvs & 0xffff0000u);
  int cap = deg < GCAP ? deg : GCAP;
  int capR = (cap + 7) & ~7;   // wave-uniform; slots [cap,capR) have w=0,s=0
  for (int i = 0; i < capR; i += 8) {
    uint pv[8]; float wsv[8];
#pragma unroll
    for (int j = 0; j < 8; j++) {
      float2 wv = sW[wslot][i + j];
      int s = sS[wslot][i + j];
      wsv[j] = (lane < 32) ? wv.x : wv.y;
      pv[j] = xw32[((size_t)s << 6) + lane];
    }
#pragma unroll
    for (int j = 0; j < 8; j++) {
      a0 += wsv[j] * __uint_as_float(pv[j] << 16);
      a1 += wsv[j] * __uint_as_float(pv[j] & 0xffff0000u);
    }
  }
  for (int i = GCAP; i < deg; i++) {
    int s = adj[r0 + i];
    float2 asv = as2[s];
    float e0 = asv.x + adv.x; e0 = e0 > 0.f ? e0 : 0.2f * e0;
    float e1 = asv.y + adv.y; e1 = e1 > 0.f ? e1 : 0.2f * e1;
    float w0 = __expf(fminf(e0, 60.f)), w1 = __expf(fminf(e1, 60.f));
    uint pv = xw32[((size_t)s << 6) + lane];
    float ws = (lane < 32) ? w0 : w1;
    a0 += ws * __uint_as_float(pv << 16);
    a1 += ws * __uint_as_float(pv & 0xffff0000u);
  }
  if (act) {
    int c0 = 2 * lane;
    float invs = (lane < 32) ? inv0 : inv1;
    float o0 = a0 * invs + ldf(bias, c0, dt);
    float o1 = a1 * invs + ldf(bias, c0 + 1, dt);
    o0 = o0 > 0.f ? o0 : 0.f;
    o1 = o1 > 0.f ? o1 : 0.f;
    uint pk = (uint)toBF(o0) | ((uint)toBF(o1) << 16);
    ((uint*)out)[(size_t)n * 64 + lane] = pk;
  }
}

// ---------------- GAT aggregate + fused pool v6: wave-sequential, barrier-free --------
// Each wave processes SEQ=4 CONSECUTIVE nodes, accumulating ReLU outputs in registers;
// flushes 2 atomicAdds/lane on graph change or at the end (batch sorted -> ~1 flush/wave,
// ~1.6M atomics total). No __syncthreads, no LDS pool: waves retire independently (the
// round-2 barrier coupled 4 waves -> block dur = max of 4 degrees, +33% time).
__global__ __launch_bounds__(256) void gat_pool6(const bf16* __restrict__ xw,
                                                 const float2* __restrict__ as2, const float2* __restrict__ ad2,
                                                 const int* __restrict__ rowstart, const int* __restrict__ adj,
                                                 const void* __restrict__ bias, float* __restrict__ pooled,
                                                 const int* __restrict__ batch, int N,
                                                 const int* __restrict__ dtflag) {
  __shared__ float2 sW[4][GCAP];
  __shared__ int sS[4][GCAP];
  int dt = dtflag[0];
  int wslot = threadIdx.x >> 6;
  int lane = threadIdx.x & 63;
  int wid = blockIdx.x * 4 + wslot;
  int n0 = wid * 4;
  const uint* xw32 = (const uint*)xw;
  int c0 = 2 * lane;
  float bias0 = ldf(bias, c0, dt), bias1 = ldf(bias, c0 + 1, dt);

  int curg = -1;
  float racc0 = 0.f, racc1 = 0.f;
  for (int k = 0; k < 4; k++) {
    int n = n0 + k;
    if (n >= N) break;
    int r0 = rowstart[n], r1 = rowstart[n + 1];
    float2 adv = ad2[n], asn = as2[n];
    int deg = r1 - r0;

    float es0 = asn.x + adv.x; es0 = es0 > 0.f ? es0 : 0.2f * es0;
    float es1 = asn.y + adv.y; es1 = es1 > 0.f ? es1 : 0.2f * es1;
    float ws0 = __expf(fminf(es0, 60.f)), ws1 = __expf(fminf(es1, 60.f));

    float den0, den1;
    {
      bool v = lane < deg;
      int s = v ? adj[r0 + lane] : 0;
      float w0 = 0.f, w1 = 0.f;
      if (v) {
        float2 asv = as2[s];
        float e0 = asv.x + adv.x; e0 = e0 > 0.f ? e0 : 0.2f * e0;
        float e1 = asv.y + adv.y; e1 = e1 > 0.f ? e1 : 0.2f * e1;
        w0 = __expf(fminf(e0, 60.f)); w1 = __expf(fminf(e1, 60.f));
      }
      sW[wslot][lane] = make_float2(w0, w1);
      sS[wslot][lane] = s;
      den0 = w0; den1 = w1;
    }
    for (int i = r0 + GCAP + lane; i < r1; i += 64) {
      int s = adj[i];
      float2 asv = as2[s];
      float e0 = asv.x + adv.x; e0 = e0 > 0.f ? e0 : 0.2f * e0;
      float e1 = asv.y + adv.y; e1 = e1 > 0.f ? e1 : 0.2f * e1;
      den0 += __expf(fminf(e0, 60.f)); den1 += __expf(fminf(e1, 60.f));
    }
#pragma unroll
    for (int off = 32; off > 0; off >>= 1) {
      den0 += __shfl_xor(den0, off, 64);
      den1 += __shfl_xor(den1, off, 64);
    }
    den0 += ws0; den1 += ws1;
    float inv0 = 1.f / (den0 + 1e-16f), inv1 = 1.f / (den1 + 1e-16f);

    float wsS = (lane < 32) ? ws0 : ws1;
    uint pvs = xw32[((size_t)n << 6) + lane];
    float a0 = wsS * __uint_as_float(pvs << 16);
    float a1 = wsS * __uint_as_float(pvs & 0xffff0000u);
    int cap = deg < GCAP ? deg : GCAP;
    int capR = (cap + 7) & ~7;
    for (int i = 0; i < capR; i += 8) {
      uint pv[8]; float wsv[8];
#pragma unroll
      for (int j = 0; j < 8; j++) {
        float2 wv = sW[wslot][i + j];
        int s = sS[wslot][i + j];
        wsv[j] = (lane < 32) ? wv.x : wv.y;
        pv[j] = xw32[((size_t)s << 6) + lane];
      }
#pragma unroll
      for (int j = 0; j < 8; j++) {
        a0 += wsv[j] * __uint_as_float(pv[j] << 16);
        a1 += wsv[j] * __uint_as_float(pv[j] & 0xffff0000u);
      }
    }
    for (int i = GCAP; i < deg; i++) {
      int s = adj[r0 + i];
      float2 asv = as2[s];
      float e0 = asv.x + adv.x; e0 = e0 > 0.f ? e0 : 0.2f * e0;
      float e1 = asv.y + adv.y; e1 = e1 > 0.f ? e1 : 0.2f * e1;
      float w0 = __expf(fminf(e0, 60.f)), w1 = __expf(fminf(e1, 60.f));
      uint pv = xw32[((size_t)s << 6) + lane];
      float ws = (lane < 32) ? w0 : w1;
      a0 += ws * __uint_as_float(pv << 16);
      a1 += ws * __uint_as_float(pv & 0xffff0000u);
    }

    float invs = (lane < 32) ? inv0 : inv1;
    float o0 = a0 * invs + bias0;
    float o1 = a1 * invs + bias1;
    o0 = o0 > 0.f ? o0 : 0.f;
    o1 = o1 > 0.f ? o1 : 0.f;

    int g = batch[n];
    if (g != curg) {
      if (curg >= 0) {
        atomicAdd(&pooled[(size_t)curg * 128 + c0], racc0);
        atomicAdd(&pooled[(size_t)curg * 128 + c0 + 1], racc1);
      }
      racc0 = 0.f; racc1 = 0.f; curg = g;
    }
    racc0 += o0; racc1 += o1;
  }
  if (curg >= 0) {
    atomicAdd(&pooled[(size_t)curg * 128 + c0], racc0);
    atomicAdd(&pooled[(size_t)curg * 128 + c0 + 1], racc1);
  }
}

// ---------------- head v4: fp32-packed weights, no per-load dtype branch ----------------
__global__ __launch_bounds__(512) void head4_kernel(
    const float* __restrict__ pooled, const void* __restrict__ x, const int* __restrict__ batch,
    const float* __restrict__ HW, void* __restrict__ out, int N, int IN,
    const int* __restrict__ dtflag) {
  const float* Wn_f = HW;
  const float* Wr_f = HW + (size_t)IN * 128;
  const float* bn_f = Wr_f + 128 * 128;
  const float* br_f = bn_f + 128;
  const float* Wc_f = br_f + 128;
  const float* bc_f = Wc_f + 256;
  int dt = dtflag[0];
  int b = blockIdx.x;
  int tid = threadIdx.x;
  int t = tid & 127, g = tid >> 7;
  __shared__ int sr0, sr1;
  __shared__ float xs[512];
  __shared__ float pl[128];
  __shared__ float pn[4][128];
  __shared__ float pg[4][128];
  __shared__ float red[128];
  if (tid == 0) {
    int lo = 0, hi = N;
    while (lo < hi) { int mid = (lo + hi) >> 1; if (batch[mid] < b) lo = mid + 1; else hi = mid; }
    sr0 = lo;
  }
  if (tid == 1) {
    int lo = 0, hi = N, b1 = b + 1;
    while (lo < hi) { int mid = (lo + hi) >> 1; if (batch[mid] < b1) lo = mid + 1; else hi = mid; }
    sr1 = lo;
  }
  __syncthreads();
  int r0 = sr0;
  float inv_cnt = 1.f / (float)(sr1 - r0);
  if (tid < 128) pl[tid] = pooled[(size_t)b * 128 + tid] * inv_cnt;
  if (dt) {
    const float* xf = (const float*)x + (size_t)r0 * IN;
    for (int k = tid; k < IN; k += 512) xs[k] = xf[k];
  } else {
    const bf16* xb = (const bf16*)x + (size_t)r0 * IN;
    for (int k = tid; k < IN; k += 512) xs[k] = toF(xb[k]);
  }
  __syncthreads();

  float n0 = 0.f, n1 = 0.f, n2 = 0.f, n3 = 0.f;
  {
    int k = g;
    for (; k + 12 < IN; k += 16) {
      n0 += xs[k]      * Wn_f[(size_t)k * 128 + t];
      n1 += xs[k + 4]  * Wn_f[(size_t)(k + 4) * 128 + t];
      n2 += xs[k + 8]  * Wn_f[(size_t)(k + 8) * 128 + t];
      n3 += xs[k + 12] * Wn_f[(size_t)(k + 12) * 128 + t];
    }
    for (; k < IN; k += 4) n0 += xs[k] * Wn_f[(size_t)k * 128 + t];
  }
  float g0 = 0.f, g1 = 0.f;
  {
    int k = g;
    for (; k + 4 < 128; k += 8) {
      g0 += pl[k]     * Wr_f[(size_t)k * 128 + t];
      g1 += pl[k + 4] * Wr_f[(size_t)(k + 4) * 128 + t];
    }
    for (; k < 128; k += 4) g0 += pl[k] * Wr_f[(size_t)k * 128 + t];
  }
  pn[g][t] = (n0 + n1) + (n2 + n3);
  pg[g][t] = g0 + g1;
  __syncthreads();
  if (tid < 128) {
    float nw = pn[0][t] + pn[1][t] + pn[2][t] + pn[3][t] + bn_f[t];
    nw = nw > 0.f ? nw : 0.f;
    float gg = pg[0][t] + pg[1][t] + pg[2][t] + pg[3][t] + br_f[t];
    gg = gg > 0.f ? gg : 0.f;
    red[t] = gg * Wc_f[t] + nw * Wc_f[128 + t];
  }
  __syncthreads();
  for (int s = 64; s > 0; s >>= 1) {
    if (tid < s) red[tid] += red[tid + s];
    __syncthreads();
  }
  if (tid == 0) {
    float z = red[0] + bc_f[0];
    float r = 1.f / (1.f + __expf(-z));
    if (dt) ((float*)out)[b] = r;
    else ((bf16*)out)[b] = __float2bfloat16(r);
  }
}

extern "C" void kernel_launch(void* const* d_in, const int* in_sizes, int n_in,
                              void* d_out, int out_size, void* d_ws, size_t ws_size,
                              hipStream_t stream) {
  const void* x   = d_in[0];
  const void* W0  = d_in[1];
  const void* aS0 = d_in[2];
  const void* aD0 = d_in[3];
  const void* b0  = d_in[4];
  const void* W1  = d_in[5];
  const void* aS1 = d_in[6];
  const void* aD1 = d_in[7];
  const void* b1  = d_in[8];
  const void* Wn  = d_in[9];
  const void* bn  = d_in[10];
  const void* Wr  = d_in[11];
  const void* br  = d_in[12];
  const void* Wc  = d_in[13];
  const void* bc  = d_in[14];
  const int* ei    = (const int*)d_in[15];
  const int* batch = (const int*)d_in[16];

  const int N = in_sizes[16];
  const int IN = in_sizes[0] / N;
  const int E = in_sizes[15] / 2;
  const int B = out_size;
  const int Kpad0 = (IN + 31) / 32 * 32;   // 320
  const int hw_elems = IN * 128 + 128 * 128 + 128 + 128 + 256 + 1;

  char* w = (char*)d_ws;
  size_t off = 0;
  auto alloc = [&](size_t bytes) { void* p = w + off; off += (bytes + 255) / 256 * 256; return p; };
  int* flag      = (int*)alloc(256);
  bf16* bufA     = (bf16*)alloc((size_t)N * 128 * 2);
  bf16* bufB     = (bf16*)alloc((size_t)N * 128 * 2);
  float2* as2    = (float2*)alloc((size_t)N * 8);
  float2* ad2    = (float2*)alloc((size_t)N * 8);
  int* cnt       = (int*)alloc((size_t)N * 4);
  int* rowstart  = (int*)alloc((size_t)(N + 1) * 4);
  int* rank      = (int*)alloc((size_t)E * 4);
  int* adj       = (int*)alloc((size_t)E * 4);
  int* csum      = (int*)alloc(1024);
  ushort* Wt0    = (ushort*)alloc((size_t)128 * Kpad0 * 2);
  ushort* Wt1    = (ushort*)alloc((size_t)128 * 128 * 2);
  float* pooled  = (float*)alloc((size_t)B * 128 * 4);
  float* HW      = (float*)alloc((size_t)hw_elems * 4);

  int ndet = in_sizes[0] < 4096 ? in_sizes[0] : 4096;
  detect_dtype<<<1, 256, 0, stream>>>(x, ndet, flag);

  // zero cnt + pooled in one dispatch (replaces two hipMemsetAsync)
  int zn = N + B * 128;
  init_zero<<<(zn + 255) / 256, 256, 0, stream>>>(cnt, pooled, N, B * 128);

  const int tb = 256;
  count_rank<<<(E + tb - 1) / tb, tb, 0, stream>>>(ei, E, cnt, rank);
  int nb = (N + 1023) / 1024;
  scan_reduce<<<nb, 256, 0, stream>>>(cnt, N, csum);
  scan_top<<<1, 256, 0, stream>>>(csum, nb, rowstart, N);
  scan_down<<<nb, 256, 0, stream>>>(cnt, N, csum, rowstart);
  scatter2<<<(E + tb - 1) / tb, tb, 0, stream>>>(ei, E, rowstart, rank, adj);

  // one consolidated parameter-pack dispatch: Wt0 (128 blocks) + Wt1 (128) + head table
  int pgrid_params = 256 + (hw_elems + 255) / 256;
  pack_params<<<pgrid_params, 256, 0, stream>>>(W0, W1, Wn, Wr, bn, br, Wc, bc,
                                                Wt0, Wt1, HW, IN, Kpad0, flag);

  int ggrid = (N + 63) / 64;
  int wgrid = ((N * 64) + 255) / 256;
  int qgrid = (N + 15) / 16;   // gat_pool6: 4 waves/block x 4 nodes/wave

  // Layer 0: fast panel path for the known shape (IN=310), fp32->bf16 conversion fused
  // into LDS staging (no separate pack pass); generic fallback otherwise
  if (IN == 310) {
    mfma_gemm4<620, false, true><<<ggrid, 256, 0, stream>>>(x, Wt0, bufA, as2, ad2, aS0, aD0, N, IN, flag);
  } else {
    mfma_gemm_gen<<<ggrid, 256, 0, stream>>>(x, Wt0, bufA, as2, ad2, aS0, aD0, N, IN, flag);
  }
  gat_agg6<<<wgrid, 256, 0, stream>>>(bufA, as2, ad2, rowstart, adj, b0, bufB, N, flag);

  // Layer 1: bf16 buffer, 256B rows, 16B-aligned; pooling fused (wave-sequential, no barrier)
  mfma_gemm4<256, true, false><<<ggrid, 256, 0, stream>>>(bufB, Wt1, bufA, as2, ad2, aS1, aD1, N, 128, flag);
  gat_pool6<<<qgrid, 256, 0, stream>>>(bufA, as2, ad2, rowstart, adj, b1, pooled, batch, N, flag);

  // Head
  head4_kernel<<<B, 512, 0, stream>>>(pooled, x, batch, HW, (void*)d_out, N, IN, flag);
}